// Round 1
// baseline (8265.722 us; speedup 1.0000x reference)
//
#include <hip/hip_runtime.h>
#include <hip/hip_bf16.h>

// ---------------------------------------------------------------------------
// TTT-MLP dual-form, fp32 correctness-first implementation.
// B=4, L=2048, C=1024, NH=16, HD=64, INTER=256, K=16, n_chunk=128, LR=1
// ---------------------------------------------------------------------------

#define B_  4
#define L_  2048
#define C_  1024
#define NH_ 16
#define HD_ 64
#define IN_ 256
#define K_  16
#define NCH_ 128
#define EPS_ 1e-6f

// ---------------- device helpers ----------------
__device__ __forceinline__ float gelu_f(float x) {
    float u = 0.79788456f * (x + 0.044715f * x * x * x);
    return 0.5f * x * (1.0f + tanhf(u));
}
__device__ __forceinline__ float dgelu_f(float x) {
    float x2 = x * x;
    float t  = tanhf(0.79788456f * x * (1.0f + 0.044715f * x2));
    return 0.5f * x * ((1.0f - t * t) * (0.79788456f + 0.1070322243f * x2))
         + 0.5f * (1.0f + t);
}

// ---------------------------------------------------------------------------
// GEMM C[m,j] = sum_c A[m,c] * W[j,c]   (A:[8192][1024], W:[1024][1024])
// mode 0: out[((b*16+h)*2048 + l)*64 + d]  (headed layout, h=j>>6, d=j&63)
// mode 1: out[m*1024 + j]                  (flat)
// grid: (128, 16), block 256. 64x64 tile, K-step 16, 4x4 per thread.
// ---------------------------------------------------------------------------
__global__ void __launch_bounds__(256)
gemm_nt(const float* __restrict__ A, const float* __restrict__ Wg,
        float* __restrict__ out, int mode)
{
    __shared__ float As[16][68];
    __shared__ float Bs[16][68];
    const int t  = threadIdx.x;
    const int tx = t & 15, ty = t >> 4;
    const int m0 = blockIdx.x * 64, j0 = blockIdx.y * 64;
    const int lm = t & 63, lc = t >> 6;   // staging: row lm, col-quad lc

    float acc[4][4];
    #pragma unroll
    for (int i = 0; i < 4; ++i)
        #pragma unroll
        for (int j = 0; j < 4; ++j) acc[i][j] = 0.f;

    for (int kt = 0; kt < C_; kt += 16) {
        float4 a4 = *(const float4*)&A [(long)(m0 + lm) * C_ + kt + lc * 4];
        float4 b4 = *(const float4*)&Wg[(long)(j0 + lm) * C_ + kt + lc * 4];
        As[lc*4+0][lm] = a4.x; As[lc*4+1][lm] = a4.y;
        As[lc*4+2][lm] = a4.z; As[lc*4+3][lm] = a4.w;
        Bs[lc*4+0][lm] = b4.x; Bs[lc*4+1][lm] = b4.y;
        Bs[lc*4+2][lm] = b4.z; Bs[lc*4+3][lm] = b4.w;
        __syncthreads();
        #pragma unroll
        for (int c = 0; c < 16; ++c) {
            float4 av = *(float4*)&As[c][ty * 4];
            float4 bv = *(float4*)&Bs[c][tx * 4];
            acc[0][0] += av.x*bv.x; acc[0][1] += av.x*bv.y; acc[0][2] += av.x*bv.z; acc[0][3] += av.x*bv.w;
            acc[1][0] += av.y*bv.x; acc[1][1] += av.y*bv.y; acc[1][2] += av.y*bv.z; acc[1][3] += av.y*bv.w;
            acc[2][0] += av.z*bv.x; acc[2][1] += av.z*bv.y; acc[2][2] += av.z*bv.z; acc[2][3] += av.z*bv.w;
            acc[3][0] += av.w*bv.x; acc[3][1] += av.w*bv.y; acc[3][2] += av.w*bv.z; acc[3][3] += av.w*bv.w;
        }
        __syncthreads();
    }

    #pragma unroll
    for (int i = 0; i < 4; ++i) {
        const int m = m0 + ty * 4 + i;
        float4 v = make_float4(acc[i][0], acc[i][1], acc[i][2], acc[i][3]);
        if (mode == 0) {
            const int bb = m >> 11, l = m & 2047;
            const int hh = blockIdx.y;            // j-tile == head (64-wide)
            const int d  = tx * 4;
            *(float4*)&out[((long)(bb * NH_ + hh) * L_ + l) * HD_ + d] = v;
        } else {
            *(float4*)&out[(long)m * C_ + j0 + tx * 4] = v;
        }
    }
}

// ---------------------------------------------------------------------------
// Gate: coeff[b,h,n,k] = sigmoid(X[l,:]·gw[h,:] + gb[h]) / (64*(k+1))
// grid 512 (16 rows each), block 256 = (lsub=t>>4, h=t&15)
// ---------------------------------------------------------------------------
__global__ void __launch_bounds__(256)
gate_kernel(const float* __restrict__ X, const float* __restrict__ gw,
            const float* __restrict__ gb, float* __restrict__ coeff)
{
    __shared__ float Xs[16][132];
    __shared__ float Gs[16][132];
    const int t = threadIdx.x;
    const int row0 = blockIdx.x * 16;
    const int lsub = t >> 4, hh = t & 15;
    const int sr = t >> 4, sc0 = (t & 15) * 8;

    float accv = 0.f;
    for (int cb = 0; cb < C_; cb += 128) {
        float4 x0 = *(const float4*)&X [(long)(row0 + sr) * C_ + cb + sc0];
        float4 x1 = *(const float4*)&X [(long)(row0 + sr) * C_ + cb + sc0 + 4];
        float4 g0 = *(const float4*)&gw[(long)sr * C_ + cb + sc0];
        float4 g1 = *(const float4*)&gw[(long)sr * C_ + cb + sc0 + 4];
        *(float4*)&Xs[sr][sc0]     = x0; *(float4*)&Xs[sr][sc0 + 4] = x1;
        *(float4*)&Gs[sr][sc0]     = g0; *(float4*)&Gs[sr][sc0 + 4] = g1;
        __syncthreads();
        #pragma unroll 8
        for (int c = 0; c < 128; ++c) accv += Xs[lsub][c] * Gs[hh][c];
        __syncthreads();
    }
    const float ilr = 1.0f / (1.0f + __expf(-(accv + gb[hh])));
    const int l  = row0 + lsub;
    const int bb = l >> 11, lb = l & 2047;
    const int n  = lb >> 4, k = lb & 15;
    coeff[((long)(bb * NH_ + hh) * NCH_ + n) * K_ + k] =
        ilr / (64.0f * (float)(k + 1));
}

// ---------------------------------------------------------------------------
// The chunked dual-form scan. One WG per (b,h). 256 threads.
// Thread t owns column t of W1 (regs), Z1/gradZ1/X2 columns (regs);
// W2 is fp32 state in LDS [256][68]; X2/X2_bar staged [16][260].
// ---------------------------------------------------------------------------
#define W2S_OFF   0
#define X2_OFF    17408          // 256*68
#define X2B_OFF   (X2_OFF + 4160)    // 16*260
#define XBT_OFF   (X2B_OFF + 4160)
#define XCT_OFF   (XBT_OFF + 1024)   // 64*16
#define ZG_OFF    (XCT_OFF + 1024)
#define M1_OFF    (ZG_OFF + 1088)    // 16*68
#define M2_OFF    (M1_OFF + 256)
#define B2_OFF    (M2_OFF + 256)
#define CF_OFF    (B2_OFF + 64)
#define LNW_OFF   (CF_OFF + 16)
#define LNB_OFF   (LNW_OFF + 64)
#define SCAN_LDS_FLOATS (LNB_OFF + 64)   // 29584
#define SCAN_LDS_BYTES  (SCAN_LDS_FLOATS * 4)

__global__ void __launch_bounds__(256, 1)
ttt_scan(const float* __restrict__ XA, const float* __restrict__ XBg,
         const float* __restrict__ XCg, const float* __restrict__ coeff,
         const float* __restrict__ W1g, const float* __restrict__ b1g,
         const float* __restrict__ W2g, const float* __restrict__ b2g,
         const float* __restrict__ lnwg, const float* __restrict__ lnbg,
         float* __restrict__ XCW)
{
    extern __shared__ float sm[];
    float* W2s = sm + W2S_OFF;
    float* X2  = sm + X2_OFF;
    float* X2b = sm + X2B_OFF;
    float* XBt = sm + XBT_OFF;
    float* XCt = sm + XCT_OFF;
    float* ZG  = sm + ZG_OFF;
    float* M1  = sm + M1_OFF;
    float* M2  = sm + M2_OFF;
    float* b2s = sm + B2_OFF;
    float* cf  = sm + CF_OFF;
    float* lnws= sm + LNW_OFF;
    float* lnbs= sm + LNB_OFF;

    const int t  = threadIdx.x;
    const int bh = blockIdx.x;
    const int h  = bh & 15;
    const int bb = bh >> 4;
    const long base = (long)bh * L_ * HD_;

    // ---- init carried state
    float w1c[64];
    #pragma unroll
    for (int d = 0; d < 64; ++d)
        w1c[d] = W1g[((h * HD_ + d) << 8) + t];        // W1[h][d][t]
    float b1r = b1g[(h << 8) + t];
    for (int dd = 0; dd < 64; dd += 4) {
        float4 v = *(const float4*)&W2g[(((long)h * IN_ + t) << 6) + dd];
        *(float4*)&W2s[t * 68 + dd] = v;
    }
    if (t < 64) {
        b2s[t]  = b2g[(h << 6) + t];
        lnws[t] = lnwg[(h << 6) + t];
        lnbs[t] = lnbg[(h << 6) + t];
    }
    __syncthreads();

    const int kk = t >> 4;          // 0..15
    const int qq = t & 15;          // 0..15
    const int d0 = qq * 4;

    for (int n = 0; n < NCH_; ++n) {
        const int l0 = n << 4;

        // ---- stage XB^T, XC^T, coeff
        {
            float4 vb = *(const float4*)&XBg[base + (long)(l0 + kk) * HD_ + d0];
            XBt[(d0+0)*16 + kk] = vb.x; XBt[(d0+1)*16 + kk] = vb.y;
            XBt[(d0+2)*16 + kk] = vb.z; XBt[(d0+3)*16 + kk] = vb.w;
            float4 vc = *(const float4*)&XCg[base + (long)(l0 + kk) * HD_ + d0];
            XCt[(d0+0)*16 + kk] = vc.x; XCt[(d0+1)*16 + kk] = vc.y;
            XCt[(d0+2)*16 + kk] = vc.z; XCt[(d0+3)*16 + kk] = vc.w;
            if (t < 16) cf[t] = coeff[((long)bh * NCH_ + n) * K_ + t];
        }
        __syncthreads();
        const float c15 = cf[15];

        // ---- phase 1: Z1 col (regs) + gelu + stage X2
        float z1[16];
        #pragma unroll
        for (int k = 0; k < 16; ++k) z1[k] = b1r;
        #pragma unroll 4
        for (int d = 0; d < 64; ++d) {
            const float w = w1c[d];
            const float* xr = &XBt[d * 16];
            #pragma unroll
            for (int k = 0; k < 16; ++k) z1[k] += xr[k] * w;
        }
        float x2c[16];
        #pragma unroll
        for (int k = 0; k < 16; ++k) {
            x2c[k] = gelu_f(z1[k]);
            X2[k * 260 + t] = x2c[k];
        }
        __syncthreads();

        // ---- phase 2: Z2[k,d] = X2@W2 + b2   (partition (kk, d0..d0+3))
        {
            float4 acc = make_float4(b2s[d0], b2s[d0+1], b2s[d0+2], b2s[d0+3]);
            #pragma unroll 4
            for (int j = 0; j < IN_; ++j) {
                const float xv = X2[kk * 260 + j];
                float4 w4 = *(float4*)&W2s[j * 68 + d0];
                acc.x += xv * w4.x; acc.y += xv * w4.y;
                acc.z += xv * w4.z; acc.w += xv * w4.w;
            }
            *(float4*)&ZG[kk * 68 + d0] = acc;
        }
        __syncthreads();

        // ---- phase 3: LN fwd + VJP -> grad_Z2 (in place in ZG)
        {
            float4 z4 = *(float4*)&ZG[kk * 68 + d0];
            float s = z4.x + z4.y + z4.z + z4.w;
            #pragma unroll
            for (int m = 1; m < 16; m <<= 1) s += __shfl_xor(s, m, 16);
            const float mu = s * (1.0f / 64.0f);
            const float e0 = z4.x - mu, e1 = z4.y - mu, e2 = z4.z - mu, e3 = z4.w - mu;
            float v = e0*e0 + e1*e1 + e2*e2 + e3*e3;
            #pragma unroll
            for (int m = 1; m < 16; m <<= 1) v += __shfl_xor(v, m, 16);
            const float rstd = rsqrtf(v * (1.0f / 64.0f) + EPS_);
            const float xh0 = e0*rstd, xh1 = e1*rstd, xh2 = e2*rstd, xh3 = e3*rstd;
            float4 xa = *(const float4*)&XA[base + (long)(l0 + kk) * HD_ + d0];
            const float lw0 = lnws[d0+0], lw1 = lnws[d0+1], lw2 = lnws[d0+2], lw3 = lnws[d0+3];
            const float g0 = (lw0*xh0 + lnbs[d0+0]) - xa.x;
            const float g1v= (lw1*xh1 + lnbs[d0+1]) - xa.y;
            const float g2 = (lw2*xh2 + lnbs[d0+2]) - xa.z;
            const float g3 = (lw3*xh3 + lnbs[d0+3]) - xa.w;
            const float wg0 = lw0*g0, wg1 = lw1*g1v, wg2 = lw2*g2, wg3 = lw3*g3;
            float sa = wg0 + wg1 + wg2 + wg3;
            float sbv = wg0*xh0 + wg1*xh1 + wg2*xh2 + wg3*xh3;
            #pragma unroll
            for (int m = 1; m < 16; m <<= 1) {
                sa  += __shfl_xor(sa,  m, 16);
                sbv += __shfl_xor(sbv, m, 16);
            }
            const float mwg  = sa  * (1.0f / 64.0f);
            const float mwgx = sbv * (1.0f / 64.0f);
            float4 gz;
            gz.x = rstd * (wg0 - mwg - xh0 * mwgx);
            gz.y = rstd * (wg1 - mwg - xh1 * mwgx);
            gz.z = rstd * (wg2 - mwg - xh2 * mwgx);
            gz.w = rstd * (wg3 - mwg - xh3 * mwgx);
            *(float4*)&ZG[kk * 68 + d0] = gz;
        }
        __syncthreads();

        // ---- phase 4: grad_Z1 col = (gZ2 @ W2^T)_col * dgelu(Z1)  (regs)
        float g1[16];
        #pragma unroll
        for (int k = 0; k < 16; ++k) g1[k] = 0.f;
        #pragma unroll 2
        for (int dd = 0; dd < 64; dd += 4) {
            float4 w4 = *(float4*)&W2s[t * 68 + dd];
            #pragma unroll
            for (int k = 0; k < 16; ++k) {
                float4 zg = *(float4*)&ZG[k * 68 + dd];
                g1[k] += zg.x*w4.x + zg.y*w4.y + zg.z*w4.z + zg.w*w4.w;
            }
        }
        #pragma unroll
        for (int k = 0; k < 16; ++k) g1[k] *= dgelu_f(z1[k]);

        // ---- phase 5: Attn1 -> M1  (partition (kk, qq))
        {
            float a = 0.f;
            #pragma unroll 8
            for (int d = 0; d < 64; ++d) a += XCt[d*16 + kk] * XBt[d*16 + qq];
            M1[kk * 16 + qq] = (qq <= kk) ? (cf[kk] * (a + 1.0f)) : 0.0f;
        }
        __syncthreads();

        // ---- phase 6: Z1_bar col -> X2_bar stage ; then W1/b1 update
        {
            float zb[16];
            #pragma unroll
            for (int k = 0; k < 16; ++k) zb[k] = b1r;
            #pragma unroll 4
            for (int d = 0; d < 64; ++d) {
                const float w = w1c[d];
                const float* xr = &XCt[d * 16];
                #pragma unroll
                for (int k = 0; k < 16; ++k) zb[k] += xr[k] * w;
            }
            #pragma unroll
            for (int k = 0; k < 16; ++k) {
                float a = 0.f;
                #pragma unroll
                for (int i = 0; i < 16; ++i) a += M1[k*16 + i] * g1[i];
                zb[k] -= a;
                X2b[k * 260 + t] = gelu_f(zb[k]);
            }
            // W1 update (uses OLD values already consumed above)
            #pragma unroll 4
            for (int d = 0; d < 64; ++d) {
                float s = 0.f;
                const float* xr = &XBt[d * 16];
                #pragma unroll
                for (int k = 0; k < 16; ++k) s += xr[k] * g1[k];
                w1c[d] -= c15 * s;
            }
            float sb1 = 0.f;
            #pragma unroll
            for (int k = 0; k < 16; ++k) sb1 += g1[k];
            b1r -= c15 * sb1;
        }
        __syncthreads();

        // ---- phase 7: Attn2 -> M2
        {
            float a = 0.f;
            #pragma unroll 4
            for (int j = 0; j < IN_; ++j) a += X2b[kk*260 + j] * X2[qq*260 + j];
            M2[kk * 16 + qq] = (qq <= kk) ? (cf[kk] * (a + 1.0f)) : 0.0f;
        }
        __syncthreads();

        // ---- phase 8: Z2_bar + write out
        {
            float4 acc = make_float4(b2s[d0], b2s[d0+1], b2s[d0+2], b2s[d0+3]);
            #pragma unroll
            for (int i = 0; i < 16; ++i) {
                const float m = M2[kk * 16 + i];
                float4 zg = *(float4*)&ZG[i * 68 + d0];
                acc.x -= m * zg.x; acc.y -= m * zg.y;
                acc.z -= m * zg.z; acc.w -= m * zg.w;
            }
            #pragma unroll 4
            for (int j = 0; j < IN_; ++j) {
                const float xv = X2b[kk * 260 + j];
                float4 w4 = *(float4*)&W2s[j * 68 + d0];
                acc.x += xv * w4.x; acc.y += xv * w4.y;
                acc.z += xv * w4.z; acc.w += xv * w4.w;
            }
            const long oidx = ((long)(bb * L_ + l0 + kk)) * C_ + h * HD_ + d0;
            *(float4*)&XCW[oidx] = acc;
        }
        __syncthreads();

        // ---- phase 9: W2/b2 update
        {
            float cg[16];
            #pragma unroll
            for (int k = 0; k < 16; ++k) cg[k] = c15 * x2c[k];
            #pragma unroll 2
            for (int dd = 0; dd < 64; dd += 4) {
                float4 w4 = *(float4*)&W2s[t * 68 + dd];
                #pragma unroll
                for (int k = 0; k < 16; ++k) {
                    float4 zg = *(float4*)&ZG[k * 68 + dd];
                    w4.x -= cg[k]*zg.x; w4.y -= cg[k]*zg.y;
                    w4.z -= cg[k]*zg.z; w4.w -= cg[k]*zg.w;
                }
                *(float4*)&W2s[t * 68 + dd] = w4;
            }
            if (t < 64) {
                float s = 0.f;
                #pragma unroll
                for (int k = 0; k < 16; ++k) s += ZG[k * 68 + t];
                b2s[t] -= c15 * s;
            }
        }
        __syncthreads();
    }
}

// ---------------------------------------------------------------------------
extern "C" void kernel_launch(void* const* d_in, const int* in_sizes, int n_in,
                              void* d_out, int out_size, void* d_ws, size_t ws_size,
                              hipStream_t stream)
{
    const float* hidden = (const float*)d_in[0];
    const float* Wq  = (const float*)d_in[1];
    const float* Wk  = (const float*)d_in[2];
    const float* Wv  = (const float*)d_in[3];
    const float* Wo  = (const float*)d_in[4];
    const float* W1g = (const float*)d_in[5];
    const float* b1g = (const float*)d_in[6];
    const float* W2g = (const float*)d_in[7];
    const float* b2g = (const float*)d_in[8];
    const float* lnw = (const float*)d_in[9];
    const float* lnb = (const float*)d_in[10];
    const float* gw  = (const float*)d_in[11];
    const float* gb  = (const float*)d_in[12];
    float* out = (float*)d_out;
    float* ws  = (float*)d_ws;

    const long PERBH = (long)B_ * NH_ * L_ * HD_;     // 8,388,608
    float* XA    = ws;
    float* XB    = ws + PERBH;
    float* XC    = ws + 2 * PERBH;
    float* coeff = ws + 3 * PERBH;                    // 131,072 floats
    float* XCW   = coeff + (long)B_ * NH_ * NCH_ * K_;

    // allow >64KB dynamic LDS for the scan kernel (idempotent host call)
    hipFuncSetAttribute(reinterpret_cast<const void*>(ttt_scan),
                        hipFuncAttributeMaxDynamicSharedMemorySize,
                        SCAN_LDS_BYTES);

    dim3 gg(128, 16, 1);
    gemm_nt<<<gg, 256, 0, stream>>>(hidden, Wq, XA, 0);
    gemm_nt<<<gg, 256, 0, stream>>>(hidden, Wk, XB, 0);
    gemm_nt<<<gg, 256, 0, stream>>>(hidden, Wv, XC, 0);
    gate_kernel<<<512, 256, 0, stream>>>(hidden, gw, gb, coeff);
    ttt_scan<<<64, 256, SCAN_LDS_BYTES, stream>>>(XA, XB, XC, coeff,
                                                  W1g, b1g, W2g, b2g,
                                                  lnw, lnb, XCW);
    gemm_nt<<<gg, 256, 0, stream>>>(XCW, Wo, out, 1);
}

// Round 2
// 2055.250 us; speedup vs baseline: 4.0218x; 4.0218x over previous
//
#include <hip/hip_runtime.h>
#include <hip/hip_bf16.h>

// ---------------------------------------------------------------------------
// TTT-MLP dual-form. MFMA-based scan (bf16 operands, fp32 state/accum).
// B=4, L=2048, C=1024, NH=16, HD=64, INTER=256, K=16, n_chunk=128, LR=1
// ---------------------------------------------------------------------------

#define B_  4
#define L_  2048
#define C_  1024
#define NH_ 16
#define HD_ 64
#define IN_ 256
#define K_  16
#define NCH_ 128
#define EPS_ 1e-6f

typedef __attribute__((ext_vector_type(8))) short  s8v;
typedef __attribute__((ext_vector_type(4))) float  f4v;
typedef __attribute__((ext_vector_type(4))) unsigned short u4v;

#define MFMA(a,b,c) __builtin_amdgcn_mfma_f32_16x16x32_bf16(a,b,c,0,0,0)

__device__ __forceinline__ unsigned short f2bf(float f) {
    unsigned int u = __float_as_uint(f);
    unsigned int r = (u + 0x7FFFu + ((u >> 16) & 1u)) >> 16;
    return (unsigned short)r;
}
__device__ __forceinline__ float bf2f(unsigned short v) {
    return __uint_as_float(((unsigned int)v) << 16);
}
__device__ __forceinline__ float gelu_f(float x) {
    float u = 0.79788456f * (x + 0.044715f * x * x * x);
    return 0.5f * x * (1.0f + tanhf(u));
}
__device__ __forceinline__ float dgelu_f(float x) {
    float x2 = x * x;
    float t  = tanhf(0.79788456f * x * (1.0f + 0.044715f * x2));
    return 0.5f * x * ((1.0f - t * t) * (0.79788456f + 0.1070322243f * x2))
         + 0.5f * (1.0f + t);
}
// K=16 fragment: 4 real bf16 in low half, zero high half (pairing-safe).
__device__ __forceinline__ s8v ld4z(const unsigned short* p) {
    u4v v = *(const u4v*)p;
    s8v a = {(short)v[0], (short)v[1], (short)v[2], (short)v[3], 0, 0, 0, 0};
    return a;
}

// ---------------------------------------------------------------------------
// fp32 GEMM C[m,j] = sum_c A[m,c] * W[j,c]  (unchanged from round 0)
// ---------------------------------------------------------------------------
__global__ void __launch_bounds__(256)
gemm_nt(const float* __restrict__ A, const float* __restrict__ Wg,
        float* __restrict__ out, int mode)
{
    __shared__ float As[16][68];
    __shared__ float Bs[16][68];
    const int t  = threadIdx.x;
    const int tx = t & 15, ty = t >> 4;
    const int m0 = blockIdx.x * 64, j0 = blockIdx.y * 64;
    const int lm = t & 63, lc = t >> 6;

    float acc[4][4];
    #pragma unroll
    for (int i = 0; i < 4; ++i)
        #pragma unroll
        for (int j = 0; j < 4; ++j) acc[i][j] = 0.f;

    for (int kt = 0; kt < C_; kt += 16) {
        float4 a4 = *(const float4*)&A [(long)(m0 + lm) * C_ + kt + lc * 4];
        float4 b4 = *(const float4*)&Wg[(long)(j0 + lm) * C_ + kt + lc * 4];
        As[lc*4+0][lm] = a4.x; As[lc*4+1][lm] = a4.y;
        As[lc*4+2][lm] = a4.z; As[lc*4+3][lm] = a4.w;
        Bs[lc*4+0][lm] = b4.x; Bs[lc*4+1][lm] = b4.y;
        Bs[lc*4+2][lm] = b4.z; Bs[lc*4+3][lm] = b4.w;
        __syncthreads();
        #pragma unroll
        for (int c = 0; c < 16; ++c) {
            float4 av = *(float4*)&As[c][ty * 4];
            float4 bv = *(float4*)&Bs[c][tx * 4];
            acc[0][0] += av.x*bv.x; acc[0][1] += av.x*bv.y; acc[0][2] += av.x*bv.z; acc[0][3] += av.x*bv.w;
            acc[1][0] += av.y*bv.x; acc[1][1] += av.y*bv.y; acc[1][2] += av.y*bv.z; acc[1][3] += av.y*bv.w;
            acc[2][0] += av.z*bv.x; acc[2][1] += av.z*bv.y; acc[2][2] += av.z*bv.z; acc[2][3] += av.z*bv.w;
            acc[3][0] += av.w*bv.x; acc[3][1] += av.w*bv.y; acc[3][2] += av.w*bv.z; acc[3][3] += av.w*bv.w;
        }
        __syncthreads();
    }

    #pragma unroll
    for (int i = 0; i < 4; ++i) {
        const int m = m0 + ty * 4 + i;
        float4 v = make_float4(acc[i][0], acc[i][1], acc[i][2], acc[i][3]);
        if (mode == 0) {
            const int bb = m >> 11, l = m & 2047;
            const int hh = blockIdx.y;
            const int d  = tx * 4;
            *(float4*)&out[((long)(bb * NH_ + hh) * L_ + l) * HD_ + d] = v;
        } else {
            *(float4*)&out[(long)m * C_ + j0 + tx * 4] = v;
        }
    }
}

// ---------------------------------------------------------------------------
// Gate (unchanged)
// ---------------------------------------------------------------------------
__global__ void __launch_bounds__(256)
gate_kernel(const float* __restrict__ X, const float* __restrict__ gw,
            const float* __restrict__ gb, float* __restrict__ coeff)
{
    __shared__ float Xs[16][132];
    __shared__ float Gs[16][132];
    const int t = threadIdx.x;
    const int row0 = blockIdx.x * 16;
    const int lsub = t >> 4, hh = t & 15;
    const int sr = t >> 4, sc0 = (t & 15) * 8;

    float accv = 0.f;
    for (int cb = 0; cb < C_; cb += 128) {
        float4 x0 = *(const float4*)&X [(long)(row0 + sr) * C_ + cb + sc0];
        float4 x1 = *(const float4*)&X [(long)(row0 + sr) * C_ + cb + sc0 + 4];
        float4 g0 = *(const float4*)&gw[(long)sr * C_ + cb + sc0];
        float4 g1 = *(const float4*)&gw[(long)sr * C_ + cb + sc0 + 4];
        *(float4*)&Xs[sr][sc0]     = x0; *(float4*)&Xs[sr][sc0 + 4] = x1;
        *(float4*)&Gs[sr][sc0]     = g0; *(float4*)&Gs[sr][sc0 + 4] = g1;
        __syncthreads();
        #pragma unroll 8
        for (int c = 0; c < 128; ++c) accv += Xs[lsub][c] * Gs[hh][c];
        __syncthreads();
    }
    const float ilr = 1.0f / (1.0f + __expf(-(accv + gb[hh])));
    const int l  = row0 + lsub;
    const int bb = l >> 11, lb = l & 2047;
    const int n  = lb >> 4, k = lb & 15;
    coeff[((long)(bb * NH_ + hh) * NCH_ + n) * K_ + k] =
        ilr / (64.0f * (float)(k + 1));
}

// ---------------------------------------------------------------------------
// MFMA scan. 64 WGs (one per b,h) x 512 threads (8 waves).
// fp32 W1/W2 state in registers (ownership = update D-tile layout);
// bf16 LDS shadows: W1Tbf [n=256][d=64] (128B rows, XOR swz),
//                   W2Tbf [d=64][j=256] (stride 264),
//                   W2bf  [j=256][d=64] (128B rows, XOR swz).
// ---------------------------------------------------------------------------
#define OFF_XBT    0          // [16][72] bf16
#define OFF_XCT    2304       // [16][72]
#define OFF_XBT64  4608       // [64][24]
#define OFF_W1T    7680       // [256][64] swz
#define OFF_W2T    40448      // [64][264]
#define OFF_W2BF   74240      // [256][64] swz
#define OFF_X2     107008     // [16][264]
#define OFF_X2T    115456     // [256][24]
#define OFF_X2B    127744     // [16][264]
#define OFF_GZ2    136192     // [16][72]
#define OFF_GZ2T   138496     // [64][24]
#define OFF_GZ1T   141568     // [256][24]
#define OFF_M1     153856     // [16][24]
#define OFF_M2     154624     // [16][24]
#define OFF_Z2F    155392     // [16][68] f32
#define OFF_B1S    159744     // 256 f32
#define OFF_B2S    160768     // 64 f32
#define OFF_LNW    161024
#define OFF_LNB    161280
#define OFF_CF     161536
#define SCAN_LDS_BYTES 161600

__global__ void __launch_bounds__(512, 1)
ttt_scan(const float* __restrict__ XAg, const float* __restrict__ XBg,
         const float* __restrict__ XCg, const float* __restrict__ coeff,
         const float* __restrict__ W1g, const float* __restrict__ b1g,
         const float* __restrict__ W2g, const float* __restrict__ b2g,
         const float* __restrict__ lnwg, const float* __restrict__ lnbg,
         float* __restrict__ XCW)
{
    extern __shared__ char smb[];
    unsigned short* XBt_u   = (unsigned short*)(smb + OFF_XBT);
    unsigned short* XCt_u   = (unsigned short*)(smb + OFF_XCT);
    unsigned short* XBT64_u = (unsigned short*)(smb + OFF_XBT64);
    char*           W1Tb    = smb + OFF_W1T;
    unsigned short* W2T_u   = (unsigned short*)(smb + OFF_W2T);
    char*           W2bfb   = smb + OFF_W2BF;
    unsigned short* X2_u    = (unsigned short*)(smb + OFF_X2);
    unsigned short* X2T_u   = (unsigned short*)(smb + OFF_X2T);
    unsigned short* X2b_u   = (unsigned short*)(smb + OFF_X2B);
    unsigned short* gZ2_u   = (unsigned short*)(smb + OFF_GZ2);
    unsigned short* gZ2T_u  = (unsigned short*)(smb + OFF_GZ2T);
    unsigned short* gZ1T_u  = (unsigned short*)(smb + OFF_GZ1T);
    unsigned short* M1_u    = (unsigned short*)(smb + OFF_M1);
    unsigned short* M2_u    = (unsigned short*)(smb + OFF_M2);
    float* Z2f  = (float*)(smb + OFF_Z2F);
    float* b1s  = (float*)(smb + OFF_B1S);
    float* b2s  = (float*)(smb + OFF_B2S);
    float* lnws = (float*)(smb + OFF_LNW);
    float* lnbs = (float*)(smb + OFF_LNB);
    float* cf   = (float*)(smb + OFF_CF);

    const int t  = threadIdx.x;
    const int w  = t >> 6;        // wave 0..7
    const int l  = t & 63;
    const int lr = l & 15;        // row/col within 16
    const int lg = l >> 4;        // k-group 0..3
    const int bh = blockIdx.x;
    const int h  = bh & 15;
    const int bb = bh >> 4;
    const long base = (long)bh * L_ * HD_;

    // ---- init fp32 state in registers
    float w1r[32], w2r[32];
    #pragma unroll
    for (int i = 0; i < 8; ++i) {
        const int idx = 8 * w + i;
        const int mt = idx >> 4, nt = idx & 15;           // W1 tiles: 4 x 16
        const int d0 = 16 * mt + 4 * lg, nn = 16 * nt + lr;
        #pragma unroll
        for (int r = 0; r < 4; ++r)
            w1r[4*i+r] = W1g[(h * HD_ + d0 + r) * IN_ + nn];
    }
    #pragma unroll
    for (int i = 0; i < 8; ++i) {
        const int idx = 8 * w + i;
        const int mt = idx >> 2, nt = idx & 3;            // W2 tiles: 16 x 4
        const int j0 = 16 * mt + 4 * lg, dn = 16 * nt + lr;
        #pragma unroll
        for (int r = 0; r < 4; ++r)
            w2r[4*i+r] = W2g[(h * IN_ + j0 + r) * HD_ + dn];
    }
    // shadows
    #pragma unroll
    for (int i = 0; i < 8; ++i) {
        const int idx = 8 * w + i;
        const int mt = idx >> 4, nt = idx & 15;
        const int d0 = 16 * mt + 4 * lg, nn = 16 * nt + lr;
        u4v pw;
        #pragma unroll
        for (int r = 0; r < 4; ++r) pw[r] = f2bf(w1r[4*i+r]);
        *(u4v*)(W1Tb + nn * 128 + ((2 * d0) ^ ((nn & 7) << 4))) = pw;
    }
    #pragma unroll
    for (int i = 0; i < 8; ++i) {
        const int idx = 8 * w + i;
        const int mt = idx >> 2, nt = idx & 3;
        const int j0 = 16 * mt + 4 * lg, dn = 16 * nt + lr;
        u4v pw;
        #pragma unroll
        for (int r = 0; r < 4; ++r) pw[r] = f2bf(w2r[4*i+r]);
        *(u4v*)(W2T_u + dn * 264 + j0) = pw;
        #pragma unroll
        for (int r = 0; r < 4; ++r) {
            const int j = j0 + r;
            *(unsigned short*)(W2bfb + j * 128 + ((2 * dn) ^ ((j & 7) << 4))) = pw[r];
        }
    }
    if (t < 256) b1s[t] = b1g[h * IN_ + t];
    if (t < 64) {
        b2s[t]  = b2g[h * HD_ + t];
        lnws[t] = lnwg[h * HD_ + t];
        lnbs[t] = lnbg[h * HD_ + t];
    }
    __syncthreads();

    float z1f[8], z1b[8];
    f4v z2bacc;

    for (int n = 0; n < NCH_; ++n) {
        const int l0 = n << 4;

        // ================= P0: stage XB/XC/coeff =================
        if (t < 256) {
            const int kk = t >> 4, qq = t & 15, d0 = 4 * qq;
            float4 vb = *(const float4*)&XBg[base + (long)(l0 + kk) * HD_ + d0];
            u4v pb;
            pb[0] = f2bf(vb.x); pb[1] = f2bf(vb.y);
            pb[2] = f2bf(vb.z); pb[3] = f2bf(vb.w);
            *(u4v*)(XBt_u + kk * 72 + d0) = pb;
            XBT64_u[(d0+0) * 24 + kk] = pb[0];
            XBT64_u[(d0+1) * 24 + kk] = pb[1];
            XBT64_u[(d0+2) * 24 + kk] = pb[2];
            XBT64_u[(d0+3) * 24 + kk] = pb[3];
            float4 vc = *(const float4*)&XCg[base + (long)(l0 + kk) * HD_ + d0];
            u4v pc;
            pc[0] = f2bf(vc.x); pc[1] = f2bf(vc.y);
            pc[2] = f2bf(vc.z); pc[3] = f2bf(vc.w);
            *(u4v*)(XCt_u + kk * 72 + d0) = pc;
        }
        if (t < 16) cf[t] = coeff[((long)bh * NCH_ + n) * K_ + t];
        __syncthreads();
        const float c15 = cf[15];

        // ================= P1: Z1 + Z1b-init (+ Attn1/M1 on wave 0) ========
        #pragma unroll
        for (int a = 0; a < 2; ++a) {
            const int n0 = 32 * w + 16 * a;
            const int nn = n0 + lr;
            const float bv = b1s[nn];
            f4v accZ = {bv, bv, bv, bv};
            f4v accB = accZ;
            #pragma unroll
            for (int ks = 0; ks < 2; ++ks) {
                s8v xb = *(const s8v*)(XBt_u + lr * 72 + 8 * lg + 32 * ks);
                s8v xc = *(const s8v*)(XCt_u + lr * 72 + 8 * lg + 32 * ks);
                s8v wf = *(const s8v*)(W1Tb + nn * 128 +
                                       ((16 * lg + 64 * ks) ^ ((nn & 7) << 4)));
                accZ = MFMA(xb, wf, accZ);
                accB = MFMA(xc, wf, accB);
            }
            u4v pkT;
            #pragma unroll
            for (int r = 0; r < 4; ++r) {
                z1f[4*a+r] = accZ[r];
                z1b[4*a+r] = accB[r];
                unsigned short bxx = f2bf(gelu_f(accZ[r]));
                X2_u[(4 * lg + r) * 264 + nn] = bxx;
                pkT[r] = bxx;
            }
            *(u4v*)(X2T_u + nn * 24 + 4 * lg) = pkT;
        }
        if (w == 0) {
            f4v at = {0.f, 0.f, 0.f, 0.f};
            #pragma unroll
            for (int ks = 0; ks < 2; ++ks) {
                s8v xc = *(const s8v*)(XCt_u + lr * 72 + 8 * lg + 32 * ks);
                s8v xb = *(const s8v*)(XBt_u + lr * 72 + 8 * lg + 32 * ks);
                at = MFMA(xc, xb, at);
            }
            #pragma unroll
            for (int r = 0; r < 4; ++r) {
                const int aa = 4 * lg + r;
                float val = (lr <= aa) ? -(cf[aa] * (at[r] + 1.0f)) : 0.0f;
                M1_u[aa * 24 + lr] = f2bf(val);
            }
        }
        __syncthreads();

        // ================= P2: Z2 = X2@W2 (waves 0..3) =================
        if (w < 4) {
            f4v acc = {0.f, 0.f, 0.f, 0.f};
            #pragma unroll
            for (int ks = 0; ks < 8; ++ks) {
                s8v xa = *(const s8v*)(X2_u + lr * 264 + 8 * lg + 32 * ks);
                s8v wt = *(const s8v*)(W2T_u + (16 * w + lr) * 264 + 8 * lg + 32 * ks);
                acc = MFMA(xa, wt, acc);
            }
            #pragma unroll
            for (int r = 0; r < 4; ++r)
                Z2f[(4 * lg + r) * 68 + 16 * w + lr] = acc[r];
        }
        __syncthreads();

        // ================= P3: LN + VJP -> gZ2 (t<256) =================
        if (t < 256) {
            const int kk = t >> 4, qq = t & 15, d0 = 4 * qq;
            float4 z = *(float4*)&Z2f[kk * 68 + d0];
            z.x += b2s[d0]; z.y += b2s[d0+1]; z.z += b2s[d0+2]; z.w += b2s[d0+3];
            float s = z.x + z.y + z.z + z.w;
            #pragma unroll
            for (int m = 1; m < 16; m <<= 1) s += __shfl_xor(s, m, 16);
            const float mu = s * (1.0f / 64.0f);
            const float e0 = z.x - mu, e1 = z.y - mu, e2 = z.z - mu, e3 = z.w - mu;
            float v = e0*e0 + e1*e1 + e2*e2 + e3*e3;
            #pragma unroll
            for (int m = 1; m < 16; m <<= 1) v += __shfl_xor(v, m, 16);
            const float rstd = rsqrtf(v * (1.0f / 64.0f) + EPS_);
            const float xh0 = e0*rstd, xh1 = e1*rstd, xh2 = e2*rstd, xh3 = e3*rstd;
            float4 xa = *(const float4*)&XAg[base + (long)(l0 + kk) * HD_ + d0];
            const float lw0 = lnws[d0+0], lw1 = lnws[d0+1], lw2 = lnws[d0+2], lw3 = lnws[d0+3];
            const float g0 = (lw0*xh0 + lnbs[d0+0]) - xa.x;
            const float g1 = (lw1*xh1 + lnbs[d0+1]) - xa.y;
            const float g2 = (lw2*xh2 + lnbs[d0+2]) - xa.z;
            const float g3 = (lw3*xh3 + lnbs[d0+3]) - xa.w;
            const float wg0 = lw0*g0, wg1 = lw1*g1, wg2 = lw2*g2, wg3 = lw3*g3;
            float sa  = wg0 + wg1 + wg2 + wg3;
            float sbv = wg0*xh0 + wg1*xh1 + wg2*xh2 + wg3*xh3;
            #pragma unroll
            for (int m = 1; m < 16; m <<= 1) {
                sa  += __shfl_xor(sa,  m, 16);
                sbv += __shfl_xor(sbv, m, 16);
            }
            const float mwg  = sa  * (1.0f / 64.0f);
            const float mwgx = sbv * (1.0f / 64.0f);
            u4v pg;
            pg[0] = f2bf(rstd * (wg0 - mwg - xh0 * mwgx));
            pg[1] = f2bf(rstd * (wg1 - mwg - xh1 * mwgx));
            pg[2] = f2bf(rstd * (wg2 - mwg - xh2 * mwgx));
            pg[3] = f2bf(rstd * (wg3 - mwg - xh3 * mwgx));
            *(u4v*)(gZ2_u + kk * 72 + d0) = pg;
            gZ2T_u[(d0+0) * 24 + kk] = pg[0];
            gZ2T_u[(d0+1) * 24 + kk] = pg[1];
            gZ2T_u[(d0+2) * 24 + kk] = pg[2];
            gZ2T_u[(d0+3) * 24 + kk] = pg[3];
        }
        __syncthreads();

        // ================= P4: gZ1 = (gZ2@W2^T) * dgelu(Z1) =================
        #pragma unroll
        for (int a = 0; a < 2; ++a) {
            const int n0 = 32 * w + 16 * a;
            const int nn = n0 + lr;
            f4v acc = {0.f, 0.f, 0.f, 0.f};
            #pragma unroll
            for (int ks = 0; ks < 2; ++ks) {
                s8v gz = *(const s8v*)(gZ2_u + lr * 72 + 8 * lg + 32 * ks);
                s8v wb = *(const s8v*)(W2bfb + nn * 128 +
                                       ((16 * lg + 64 * ks) ^ ((nn & 7) << 4)));
                acc = MFMA(gz, wb, acc);
            }
            u4v pk;
            #pragma unroll
            for (int r = 0; r < 4; ++r)
                pk[r] = f2bf(acc[r] * dgelu_f(z1f[4*a+r]));
            *(u4v*)(gZ1T_u + nn * 24 + 4 * lg) = pk;
        }
        __syncthreads();

        // ============ P5: Z1b finish -> X2b ; W1 update ; b1 update ========
        #pragma unroll
        for (int a = 0; a < 2; ++a) {
            const int nn = 32 * w + 16 * a + lr;
            s8v ml = ld4z(M1_u + lr * 24 + 4 * lg);
            s8v gr = ld4z(gZ1T_u + nn * 24 + 4 * lg);
            f4v acc = {z1b[4*a], z1b[4*a+1], z1b[4*a+2], z1b[4*a+3]};
            acc = MFMA(ml, gr, acc);
            #pragma unroll
            for (int r = 0; r < 4; ++r)
                X2b_u[(4 * lg + r) * 264 + nn] = f2bf(gelu_f(acc[r]));
        }
        #pragma unroll
        for (int i = 0; i < 8; ++i) {
            const int idx = 8 * w + i;
            const int mt = idx >> 4, nt = idx & 15;
            s8v la = ld4z(XBT64_u + (16 * mt + lr) * 24 + 4 * lg);
            s8v rb = ld4z(gZ1T_u + (16 * nt + lr) * 24 + 4 * lg);
            f4v uz = {0.f, 0.f, 0.f, 0.f};
            uz = MFMA(la, rb, uz);
            u4v pw;
            #pragma unroll
            for (int r = 0; r < 4; ++r) {
                w1r[4*i+r] -= c15 * uz[r];
                pw[r] = f2bf(w1r[4*i+r]);
            }
            const int nn1 = 16 * nt + lr;
            const int d0  = 16 * mt + 4 * lg;
            *(u4v*)(W1Tb + nn1 * 128 + ((2 * d0) ^ ((nn1 & 7) << 4))) = pw;
        }
        if (t < 256) {
            float s = 0.f;
            #pragma unroll
            for (int q = 0; q < 4; ++q) {
                u4v v = *(const u4v*)(gZ1T_u + t * 24 + 4 * q);
                s += bf2f(v[0]) + bf2f(v[1]) + bf2f(v[2]) + bf2f(v[3]);
            }
            b1s[t] -= c15 * s;
        }
        __syncthreads();

        // ===== P6: Attn2/M2 (w0), Z2b-main (w1..4), W2-upd mfma (all) ======
        if (w == 0) {
            f4v at2 = {0.f, 0.f, 0.f, 0.f};
            #pragma unroll
            for (int ks = 0; ks < 8; ++ks) {
                s8v xb2 = *(const s8v*)(X2b_u + lr * 264 + 8 * lg + 32 * ks);
                s8v x2r = *(const s8v*)(X2_u  + lr * 264 + 8 * lg + 32 * ks);
                at2 = MFMA(xb2, x2r, at2);
            }
            #pragma unroll
            for (int r = 0; r < 4; ++r) {
                const int aa = 4 * lg + r;
                float val = (lr <= aa) ? -(cf[aa] * (at2[r] + 1.0f)) : 0.0f;
                M2_u[aa * 24 + lr] = f2bf(val);
            }
        } else if (w <= 4) {
            const int dt = w - 1;
            const float bv = b2s[16 * dt + lr];
            z2bacc = (f4v){bv, bv, bv, bv};
            #pragma unroll
            for (int ks = 0; ks < 8; ++ks) {
                s8v xb2 = *(const s8v*)(X2b_u + lr * 264 + 8 * lg + 32 * ks);
                s8v wt  = *(const s8v*)(W2T_u + (16 * dt + lr) * 264 + 8 * lg + 32 * ks);
                z2bacc = MFMA(xb2, wt, z2bacc);
            }
        }
        #pragma unroll
        for (int i = 0; i < 8; ++i) {
            const int idx = 8 * w + i;
            const int mt = idx >> 2, nt = idx & 3;
            s8v la = ld4z(X2T_u  + (16 * mt + lr) * 24 + 4 * lg);
            s8v rb = ld4z(gZ2T_u + (16 * nt + lr) * 24 + 4 * lg);
            f4v uz = {0.f, 0.f, 0.f, 0.f};
            uz = MFMA(la, rb, uz);
            #pragma unroll
            for (int r = 0; r < 4; ++r) w2r[4*i+r] -= c15 * uz[r];
        }
        __syncthreads();

        // ===== P7: Z2b finalize + store ; W2 shadow writes ; b2 update =====
        if (w >= 1 && w <= 4) {
            const int dt = w - 1;
            s8v ml = ld4z(M2_u + lr * 24 + 4 * lg);
            s8v gr = ld4z(gZ2T_u + (16 * dt + lr) * 24 + 4 * lg);
            z2bacc = MFMA(ml, gr, z2bacc);
            #pragma unroll
            for (int r = 0; r < 4; ++r)
                XCW[((long)(bb * L_ + l0 + 4 * lg + r)) * C_ + h * HD_ + 16 * dt + lr]
                    = z2bacc[r];
        }
        #pragma unroll
        for (int i = 0; i < 8; ++i) {
            const int idx = 8 * w + i;
            const int mt = idx >> 2, nt = idx & 3;
            const int j0 = 16 * mt + 4 * lg, dn = 16 * nt + lr;
            u4v pw;
            #pragma unroll
            for (int r = 0; r < 4; ++r) pw[r] = f2bf(w2r[4*i+r]);
            *(u4v*)(W2T_u + dn * 264 + j0) = pw;
            #pragma unroll
            for (int r = 0; r < 4; ++r) {
                const int j = j0 + r;
                *(unsigned short*)(W2bfb + j * 128 + ((2 * dn) ^ ((j & 7) << 4))) = pw[r];
            }
        }
        if (t < 64) {
            float s = 0.f;
            #pragma unroll
            for (int q = 0; q < 4; ++q) {
                u4v v = *(const u4v*)(gZ2T_u + t * 24 + 4 * q);
                s += bf2f(v[0]) + bf2f(v[1]) + bf2f(v[2]) + bf2f(v[3]);
            }
            b2s[t] -= c15 * s;
        }
        __syncthreads();
    }
}

// ---------------------------------------------------------------------------
extern "C" void kernel_launch(void* const* d_in, const int* in_sizes, int n_in,
                              void* d_out, int out_size, void* d_ws, size_t ws_size,
                              hipStream_t stream)
{
    const float* hidden = (const float*)d_in[0];
    const float* Wq  = (const float*)d_in[1];
    const float* Wk  = (const float*)d_in[2];
    const float* Wv  = (const float*)d_in[3];
    const float* Wo  = (const float*)d_in[4];
    const float* W1g = (const float*)d_in[5];
    const float* b1g = (const float*)d_in[6];
    const float* W2g = (const float*)d_in[7];
    const float* b2g = (const float*)d_in[8];
    const float* lnw = (const float*)d_in[9];
    const float* lnb = (const float*)d_in[10];
    const float* gw  = (const float*)d_in[11];
    const float* gb  = (const float*)d_in[12];
    float* out = (float*)d_out;
    float* ws  = (float*)d_ws;

    const long PERBH = (long)B_ * NH_ * L_ * HD_;
    float* XA    = ws;
    float* XB    = ws + PERBH;
    float* XC    = ws + 2 * PERBH;
    float* coeff = ws + 3 * PERBH;
    float* XCW   = coeff + (long)B_ * NH_ * NCH_ * K_;

    hipFuncSetAttribute(reinterpret_cast<const void*>(ttt_scan),
                        hipFuncAttributeMaxDynamicSharedMemorySize,
                        SCAN_LDS_BYTES);

    dim3 gg(128, 16, 1);
    gemm_nt<<<gg, 256, 0, stream>>>(hidden, Wq, XA, 0);
    gemm_nt<<<gg, 256, 0, stream>>>(hidden, Wk, XB, 0);
    gemm_nt<<<gg, 256, 0, stream>>>(hidden, Wv, XC, 0);
    gate_kernel<<<512, 256, 0, stream>>>(hidden, gw, gb, coeff);
    ttt_scan<<<64, 512, SCAN_LDS_BYTES, stream>>>(XA, XB, XC, coeff,
                                                  W1g, b1g, W2g, b2g,
                                                  lnw, lnb, XCW);
    gemm_nt<<<gg, 256, 0, stream>>>(XCW, Wo, out, 1);
}

// Round 4
// 1120.825 us; speedup vs baseline: 7.3747x; 1.8337x over previous
//
#include <hip/hip_runtime.h>
#include <hip/hip_bf16.h>

// ---------------------------------------------------------------------------
// TTT-MLP dual-form. bf16-MFMA GEMMs + MFMA scan (fp32 state/accum).
// B=4, L=2048, C=1024, NH=16, HD=64, INTER=256, K=16, n_chunk=128, LR=1
// ---------------------------------------------------------------------------

#define B_  4
#define L_  2048
#define C_  1024
#define NH_ 16
#define HD_ 64
#define IN_ 256
#define K_  16
#define NCH_ 128
#define EPS_ 1e-6f

typedef unsigned short ushort_t;
typedef __attribute__((ext_vector_type(8))) short  s8v;
typedef __attribute__((ext_vector_type(4))) float  f4v;
typedef __attribute__((ext_vector_type(4))) unsigned short u4v;

#define MFMA(a,b,c) __builtin_amdgcn_mfma_f32_16x16x32_bf16(a,b,c,0,0,0)

#define LOAD_LDS16(gp, lp) \
  __builtin_amdgcn_global_load_lds((const __attribute__((address_space(1))) void*)(gp), \
                                   (__attribute__((address_space(3))) void*)(lp), 16, 0, 0)

__device__ __forceinline__ ushort_t f2bf(float f) {
    unsigned int u = __float_as_uint(f);
    unsigned int r = (u + 0x7FFFu + ((u >> 16) & 1u)) >> 16;
    return (ushort_t)r;
}
__device__ __forceinline__ float bf2f(ushort_t v) {
    return __uint_as_float(((unsigned int)v) << 16);
}
__device__ __forceinline__ float gelu_f(float x) {
    float u = 0.79788456f * (x + 0.044715f * x * x * x);
    return 0.5f * x * (1.0f + tanhf(u));
}
__device__ __forceinline__ float dgelu_f(float x) {
    float x2 = x * x;
    float t  = tanhf(0.79788456f * x * (1.0f + 0.044715f * x2));
    return 0.5f * x * ((1.0f - t * t) * (0.79788456f + 0.1070322243f * x2))
         + 0.5f * (1.0f + t);
}
// K=16 fragment: 4 real bf16 in low half, zero high half (pairing-safe).
__device__ __forceinline__ s8v ld4z(const ushort_t* p) {
    u4v v = *(const u4v*)p;
    s8v a = {(short)v[0], (short)v[1], (short)v[2], (short)v[3], 0, 0, 0, 0};
    return a;
}

// ---------------------------------------------------------------------------
// Cast fp32 -> bf16: hidden (8.39M) then Wq,Wk,Wv,Wo (1.05M each), contiguous
// dst. 6144 blocks x 256 thr x 8 elems.
// ---------------------------------------------------------------------------
__global__ void __launch_bounds__(256)
cast_kernel(const float* __restrict__ hid, const float* __restrict__ wq,
            const float* __restrict__ wk, const float* __restrict__ wv,
            const float* __restrict__ wo, ushort_t* __restrict__ dst)
{
    const long i = ((long)blockIdx.x * 256 + threadIdx.x) * 8;
    const float* src; long off;
    if (i < 8388608L)        { src = hid; off = i; }
    else if (i < 9437184L)   { src = wq;  off = i - 8388608L; }
    else if (i < 10485760L)  { src = wk;  off = i - 9437184L; }
    else if (i < 11534336L)  { src = wv;  off = i - 10485760L; }
    else                     { src = wo;  off = i - 11534336L; }
    float4 a = *(const float4*)(src + off);
    float4 b = *(const float4*)(src + off + 4);
    u4v p0, p1;
    p0[0] = f2bf(a.x); p0[1] = f2bf(a.y); p0[2] = f2bf(a.z); p0[3] = f2bf(a.w);
    p1[0] = f2bf(b.x); p1[1] = f2bf(b.y); p1[2] = f2bf(b.z); p1[3] = f2bf(b.w);
    *(u4v*)(dst + i)     = p0;
    *(u4v*)(dst + i + 4) = p1;
}

// ---------------------------------------------------------------------------
// bf16 MFMA GEMM: C[m,j] = sum_c A[m,c]*Bm[j,c].  M=8192, N=K=1024.
// 128x128 tile, BK=32, 256 thr (4 waves 2x2), 4x4 16x16x32 frags/wave.
// Fragment-major LDS (16B unit == lane) => conflict-free, global_load_lds x16.
// mode 0: fp32 headed   mode 1: bf16 headed   mode 2: fp32 flat
// grid 512 1-D: mtile = wg>>3, ntile = wg&7 (XCD keeps one B-panel).
// ---------------------------------------------------------------------------
__global__ void __launch_bounds__(256, 2)
gemm_bf16(const ushort_t* __restrict__ A, const ushort_t* __restrict__ Bm,
          void* __restrict__ outp, int mode)
{
    __shared__ char lds[16384];
    char* Al = lds;
    char* Bl = lds + 8192;
    const int t  = threadIdx.x;
    const int w  = t >> 6, l = t & 63;
    const int lr = l & 15, lg = l >> 4;
    const int wm = w >> 1, wn = w & 1;
    const int wg = blockIdx.x;
    const int m0 = (wg >> 3) * 128, n0 = (wg & 7) * 128;

    f4v acc[4][4];
    #pragma unroll
    for (int i = 0; i < 4; ++i)
        #pragma unroll
        for (int j = 0; j < 4; ++j)
            acc[i][j] = (f4v){0.f, 0.f, 0.f, 0.f};

    // per-lane global source offsets (fragment-major)
    const long arow0 = (long)(m0 + w * 16 + lr) * C_ + lg * 8;
    const long arow1 = (long)(m0 + (w + 4) * 16 + lr) * C_ + lg * 8;
    const long brow0 = (long)(n0 + w * 16 + lr) * C_ + lg * 8;
    const long brow1 = (long)(n0 + (w + 4) * 16 + lr) * C_ + lg * 8;

    for (int ks = 0; ks < C_ / 32; ++ks) {
        const int k0 = ks * 32;
        LOAD_LDS16(A  + arow0 + k0, Al + w * 1024);
        LOAD_LDS16(A  + arow1 + k0, Al + (w + 4) * 1024);
        LOAD_LDS16(Bm + brow0 + k0, Bl + w * 1024);
        LOAD_LDS16(Bm + brow1 + k0, Bl + (w + 4) * 1024);
        __syncthreads();
        s8v af[4], bfr[4];
        #pragma unroll
        for (int i = 0; i < 4; ++i)
            af[i] = *(const s8v*)(Al + (wm * 4 + i) * 1024 + l * 16);
        #pragma unroll
        for (int j = 0; j < 4; ++j)
            bfr[j] = *(const s8v*)(Bl + (wn * 4 + j) * 1024 + l * 16);
        #pragma unroll
        for (int i = 0; i < 4; ++i)
            #pragma unroll
            for (int j = 0; j < 4; ++j)
                acc[i][j] = MFMA(af[i], bfr[j], acc[i][j]);
        __syncthreads();
    }

    #pragma unroll
    for (int i = 0; i < 4; ++i) {
        #pragma unroll
        for (int j = 0; j < 4; ++j) {
            #pragma unroll
            for (int r = 0; r < 4; ++r) {
                const int grow = m0 + wm * 64 + i * 16 + lg * 4 + r;
                const int gcol = n0 + wn * 64 + j * 16 + lr;
                const float v = acc[i][j][r];
                if (mode == 2) {
                    ((float*)outp)[(long)grow * C_ + gcol] = v;
                } else {
                    const int bbv = grow >> 11, ll = grow & 2047;
                    const int hv = gcol >> 6, dv = gcol & 63;
                    const long addr = ((long)(bbv * NH_ + hv) * L_ + ll) * HD_ + dv;
                    if (mode == 0) ((float*)outp)[addr] = v;
                    else           ((ushort_t*)outp)[addr] = f2bf(v);
                }
            }
        }
    }
}

// ---------------------------------------------------------------------------
// Gate (unchanged, fp32 hidden)
// ---------------------------------------------------------------------------
__global__ void __launch_bounds__(256)
gate_kernel(const float* __restrict__ X, const float* __restrict__ gw,
            const float* __restrict__ gb, float* __restrict__ coeff)
{
    __shared__ float Xs[16][132];
    __shared__ float Gs[16][132];
    const int t = threadIdx.x;
    const int row0 = blockIdx.x * 16;
    const int lsub = t >> 4, hh = t & 15;
    const int sr = t >> 4, sc0 = (t & 15) * 8;

    float accv = 0.f;
    for (int cb = 0; cb < C_; cb += 128) {
        float4 x0 = *(const float4*)&X [(long)(row0 + sr) * C_ + cb + sc0];
        float4 x1 = *(const float4*)&X [(long)(row0 + sr) * C_ + cb + sc0 + 4];
        float4 g0 = *(const float4*)&gw[(long)sr * C_ + cb + sc0];
        float4 g1 = *(const float4*)&gw[(long)sr * C_ + cb + sc0 + 4];
        *(float4*)&Xs[sr][sc0]     = x0; *(float4*)&Xs[sr][sc0 + 4] = x1;
        *(float4*)&Gs[sr][sc0]     = g0; *(float4*)&Gs[sr][sc0 + 4] = g1;
        __syncthreads();
        #pragma unroll 8
        for (int c = 0; c < 128; ++c) accv += Xs[lsub][c] * Gs[hh][c];
        __syncthreads();
    }
    const float ilr = 1.0f / (1.0f + __expf(-(accv + gb[hh])));
    const int l  = row0 + lsub;
    const int bb = l >> 11, lb = l & 2047;
    const int n  = lb >> 4, k = lb & 15;
    coeff[((long)(bb * NH_ + hh) * NCH_ + n) * K_ + k] =
        ilr / (64.0f * (float)(k + 1));
}

// ---------------------------------------------------------------------------
// MFMA scan. 64 WGs x 512 threads. bf16 XB/XC in, bf16 XCW out, fp32 XA.
// Register prefetch of chunk n+1 inputs (hides global latency on serial path).
// ---------------------------------------------------------------------------
#define OFF_XBT    0          // [16][72] bf16
#define OFF_XCT    2304       // [16][72]
#define OFF_XBT64  4608       // [64][24]
#define OFF_W1T    7680       // [256][64] swz
#define OFF_W2T    40448      // [64][264]
#define OFF_W2BF   74240      // [256][64] swz
#define OFF_X2     107008     // [16][264]
#define OFF_X2T    115456     // [256][24]
#define OFF_X2B    127744     // [16][264]
#define OFF_GZ2    136192     // [16][72]
#define OFF_GZ2T   138496     // [64][24]
#define OFF_GZ1T   141568     // [256][24]
#define OFF_M1     153856     // [16][24]
#define OFF_M2     154624     // [16][24]
#define OFF_Z2F    155392     // [16][68] f32
#define OFF_B1S    159744     // 256 f32
#define OFF_B2S    160768     // 64 f32
#define OFF_LNW    161024
#define OFF_LNB    161280
#define OFF_CF     161536
#define SCAN_LDS_BYTES 161600

__global__ void __launch_bounds__(512, 1)
ttt_scan(const float* __restrict__ XAg, const ushort_t* __restrict__ XBg,
         const ushort_t* __restrict__ XCg, const float* __restrict__ coeff,
         const float* __restrict__ W1g, const float* __restrict__ b1g,
         const float* __restrict__ W2g, const float* __restrict__ b2g,
         const float* __restrict__ lnwg, const float* __restrict__ lnbg,
         ushort_t* __restrict__ XCWb)
{
    extern __shared__ char smb[];
    ushort_t* XBt_u   = (ushort_t*)(smb + OFF_XBT);
    ushort_t* XCt_u   = (ushort_t*)(smb + OFF_XCT);
    ushort_t* XBT64_u = (ushort_t*)(smb + OFF_XBT64);
    char*     W1Tb    = smb + OFF_W1T;
    ushort_t* W2T_u   = (ushort_t*)(smb + OFF_W2T);
    char*     W2bfb   = smb + OFF_W2BF;
    ushort_t* X2_u    = (ushort_t*)(smb + OFF_X2);
    ushort_t* X2T_u   = (ushort_t*)(smb + OFF_X2T);
    ushort_t* X2b_u   = (ushort_t*)(smb + OFF_X2B);
    ushort_t* gZ2_u   = (ushort_t*)(smb + OFF_GZ2);
    ushort_t* gZ2T_u  = (ushort_t*)(smb + OFF_GZ2T);
    ushort_t* gZ1T_u  = (ushort_t*)(smb + OFF_GZ1T);
    ushort_t* M1_u    = (ushort_t*)(smb + OFF_M1);
    ushort_t* M2_u    = (ushort_t*)(smb + OFF_M2);
    float* Z2f  = (float*)(smb + OFF_Z2F);
    float* b1s  = (float*)(smb + OFF_B1S);
    float* b2s  = (float*)(smb + OFF_B2S);
    float* lnws = (float*)(smb + OFF_LNW);
    float* lnbs = (float*)(smb + OFF_LNB);
    float* cf   = (float*)(smb + OFF_CF);

    const int t  = threadIdx.x;
    const int w  = t >> 6;
    const int l  = t & 63;
    const int lr = l & 15;
    const int lg = l >> 4;
    const int bh = blockIdx.x;
    const int h  = bh & 15;
    const int bb = bh >> 4;
    const long base = (long)bh * L_ * HD_;

    // ---- init fp32 state in registers
    float w1r[32], w2r[32];
    #pragma unroll
    for (int i = 0; i < 8; ++i) {
        const int idx = 8 * w + i;
        const int mt = idx >> 4, nt = idx & 15;
        const int d0 = 16 * mt + 4 * lg, nn = 16 * nt + lr;
        #pragma unroll
        for (int r = 0; r < 4; ++r)
            w1r[4*i+r] = W1g[(h * HD_ + d0 + r) * IN_ + nn];
    }
    #pragma unroll
    for (int i = 0; i < 8; ++i) {
        const int idx = 8 * w + i;
        const int mt = idx >> 2, nt = idx & 3;
        const int j0 = 16 * mt + 4 * lg, dn = 16 * nt + lr;
        #pragma unroll
        for (int r = 0; r < 4; ++r)
            w2r[4*i+r] = W2g[(h * IN_ + j0 + r) * HD_ + dn];
    }
    #pragma unroll
    for (int i = 0; i < 8; ++i) {
        const int idx = 8 * w + i;
        const int mt = idx >> 4, nt = idx & 15;
        const int d0 = 16 * mt + 4 * lg, nn = 16 * nt + lr;
        u4v pw;
        #pragma unroll
        for (int r = 0; r < 4; ++r) pw[r] = f2bf(w1r[4*i+r]);
        *(u4v*)(W1Tb + nn * 128 + ((2 * d0) ^ ((nn & 7) << 4))) = pw;
    }
    #pragma unroll
    for (int i = 0; i < 8; ++i) {
        const int idx = 8 * w + i;
        const int mt = idx >> 2, nt = idx & 3;
        const int j0 = 16 * mt + 4 * lg, dn = 16 * nt + lr;
        u4v pw;
        #pragma unroll
        for (int r = 0; r < 4; ++r) pw[r] = f2bf(w2r[4*i+r]);
        *(u4v*)(W2T_u + dn * 264 + j0) = pw;
        #pragma unroll
        for (int r = 0; r < 4; ++r) {
            const int j = j0 + r;
            *(ushort_t*)(W2bfb + j * 128 + ((2 * dn) ^ ((j & 7) << 4))) = pw[r];
        }
    }
    if (t < 256) b1s[t] = b1g[h * IN_ + t];
    if (t < 64) {
        b2s[t]  = b2g[h * HD_ + t];
        lnws[t] = lnwg[h * HD_ + t];
        lnbs[t] = lnbg[h * HD_ + t];
    }
    __syncthreads();

    float z1f[8], z1b[8];
    f4v z2bacc;

    // ---- prefetch chunk 0 inputs
    const int pkk = t >> 4, pd0 = (t & 15) * 4;
    u4v pf_b, pf_c; float4 pf_a; float pf_cf;
    if (t < 256) {
        pf_b = *(const u4v*)(XBg + base + (long)pkk * HD_ + pd0);
        pf_c = *(const u4v*)(XCg + base + (long)pkk * HD_ + pd0);
        pf_a = *(const float4*)&XAg[base + (long)pkk * HD_ + pd0];
    }
    if (t < 16) pf_cf = coeff[(long)bh * NCH_ * K_ + t];

    for (int n = 0; n < NCH_; ++n) {
        const int l0 = n << 4;
        float4 cur_a = pf_a;

        // ================= P0: write prefetched XB/XC/coeff to LDS ========
        if (t < 256) {
            *(u4v*)(XBt_u + pkk * 72 + pd0) = pf_b;
            XBT64_u[(pd0+0) * 24 + pkk] = pf_b[0];
            XBT64_u[(pd0+1) * 24 + pkk] = pf_b[1];
            XBT64_u[(pd0+2) * 24 + pkk] = pf_b[2];
            XBT64_u[(pd0+3) * 24 + pkk] = pf_b[3];
            *(u4v*)(XCt_u + pkk * 72 + pd0) = pf_c;
        }
        if (t < 16) cf[t] = pf_cf;
        __syncthreads();
        const float c15 = cf[15];

        // ---- issue prefetch for chunk n+1 (hidden under this chunk's work)
        if (n + 1 < NCH_) {
            const long nb = base + (long)(l0 + 16 + pkk) * HD_ + pd0;
            if (t < 256) {
                pf_b = *(const u4v*)(XBg + nb);
                pf_c = *(const u4v*)(XCg + nb);
                pf_a = *(const float4*)&XAg[nb];
            }
            if (t < 16) pf_cf = coeff[((long)bh * NCH_ + n + 1) * K_ + t];
        }

        // ================= P1: Z1 + Z1b-init (+ Attn1/M1 on wave 0) ========
        #pragma unroll
        for (int a = 0; a < 2; ++a) {
            const int n0 = 32 * w + 16 * a;
            const int nn = n0 + lr;
            const float bv = b1s[nn];
            f4v accZ = {bv, bv, bv, bv};
            f4v accB = accZ;
            #pragma unroll
            for (int ks = 0; ks < 2; ++ks) {
                s8v xb = *(const s8v*)(XBt_u + lr * 72 + 8 * lg + 32 * ks);
                s8v xc = *(const s8v*)(XCt_u + lr * 72 + 8 * lg + 32 * ks);
                s8v wf = *(const s8v*)(W1Tb + nn * 128 +
                                       ((16 * lg + 64 * ks) ^ ((nn & 7) << 4)));
                accZ = MFMA(xb, wf, accZ);
                accB = MFMA(xc, wf, accB);
            }
            u4v pkT;
            #pragma unroll
            for (int r = 0; r < 4; ++r) {
                z1f[4*a+r] = accZ[r];
                z1b[4*a+r] = accB[r];
                ushort_t bxx = f2bf(gelu_f(accZ[r]));
                X2_u[(4 * lg + r) * 264 + nn] = bxx;
                pkT[r] = bxx;
            }
            *(u4v*)(X2T_u + nn * 24 + 4 * lg) = pkT;
        }
        if (w == 0) {
            f4v at = {0.f, 0.f, 0.f, 0.f};
            #pragma unroll
            for (int ks = 0; ks < 2; ++ks) {
                s8v xc = *(const s8v*)(XCt_u + lr * 72 + 8 * lg + 32 * ks);
                s8v xb = *(const s8v*)(XBt_u + lr * 72 + 8 * lg + 32 * ks);
                at = MFMA(xc, xb, at);
            }
            #pragma unroll
            for (int r = 0; r < 4; ++r) {
                const int aa = 4 * lg + r;
                float val = (lr <= aa) ? -(cf[aa] * (at[r] + 1.0f)) : 0.0f;
                M1_u[aa * 24 + lr] = f2bf(val);
            }
        }
        __syncthreads();

        // ================= P2: Z2 = X2@W2 (waves 0..3) =================
        if (w < 4) {
            f4v acc = {0.f, 0.f, 0.f, 0.f};
            #pragma unroll
            for (int ks = 0; ks < 8; ++ks) {
                s8v xa = *(const s8v*)(X2_u + lr * 264 + 8 * lg + 32 * ks);
                s8v wt = *(const s8v*)(W2T_u + (16 * w + lr) * 264 + 8 * lg + 32 * ks);
                acc = MFMA(xa, wt, acc);
            }
            #pragma unroll
            for (int r = 0; r < 4; ++r)
                Z2f[(4 * lg + r) * 68 + 16 * w + lr] = acc[r];
        }
        __syncthreads();

        // ================= P3: LN + VJP -> gZ2 (t<256) =================
        if (t < 256) {
            const int kk = t >> 4, d0 = pd0;
            float4 z = *(float4*)&Z2f[kk * 68 + d0];
            z.x += b2s[d0]; z.y += b2s[d0+1]; z.z += b2s[d0+2]; z.w += b2s[d0+3];
            float s = z.x + z.y + z.z + z.w;
            #pragma unroll
            for (int m = 1; m < 16; m <<= 1) s += __shfl_xor(s, m, 16);
            const float mu = s * (1.0f / 64.0f);
            const float e0 = z.x - mu, e1 = z.y - mu, e2 = z.z - mu, e3 = z.w - mu;
            float v = e0*e0 + e1*e1 + e2*e2 + e3*e3;
            #pragma unroll
            for (int m = 1; m < 16; m <<= 1) v += __shfl_xor(v, m, 16);
            const float rstd = rsqrtf(v * (1.0f / 64.0f) + EPS_);
            const float xh0 = e0*rstd, xh1 = e1*rstd, xh2 = e2*rstd, xh3 = e3*rstd;
            const float lw0 = lnws[d0+0], lw1 = lnws[d0+1], lw2 = lnws[d0+2], lw3 = lnws[d0+3];
            const float g0 = (lw0*xh0 + lnbs[d0+0]) - cur_a.x;
            const float g1 = (lw1*xh1 + lnbs[d0+1]) - cur_a.y;
            const float g2 = (lw2*xh2 + lnbs[d0+2]) - cur_a.z;
            const float g3 = (lw3*xh3 + lnbs[d0+3]) - cur_a.w;
            const float wg0 = lw0*g0, wg1 = lw1*g1, wg2 = lw2*g2, wg3 = lw3*g3;
            float sa  = wg0 + wg1 + wg2 + wg3;
            float sbv = wg0*xh0 + wg1*xh1 + wg2*xh2 + wg3*xh3;
            #pragma unroll
            for (int m = 1; m < 16; m <<= 1) {
                sa  += __shfl_xor(sa,  m, 16);
                sbv += __shfl_xor(sbv, m, 16);
            }
            const float mwg  = sa  * (1.0f / 64.0f);
            const float mwgx = sbv * (1.0f / 64.0f);
            u4v pg;
            pg[0] = f2bf(rstd * (wg0 - mwg - xh0 * mwgx));
            pg[1] = f2bf(rstd * (wg1 - mwg - xh1 * mwgx));
            pg[2] = f2bf(rstd * (wg2 - mwg - xh2 * mwgx));
            pg[3] = f2bf(rstd * (wg3 - mwg - xh3 * mwgx));
            *(u4v*)(gZ2_u + kk * 72 + d0) = pg;
            gZ2T_u[(d0+0) * 24 + kk] = pg[0];
            gZ2T_u[(d0+1) * 24 + kk] = pg[1];
            gZ2T_u[(d0+2) * 24 + kk] = pg[2];
            gZ2T_u[(d0+3) * 24 + kk] = pg[3];
        }
        __syncthreads();

        // ================= P4: gZ1 = (gZ2@W2^T) * dgelu(Z1) =================
        #pragma unroll
        for (int a = 0; a < 2; ++a) {
            const int n0 = 32 * w + 16 * a;
            const int nn = n0 + lr;
            f4v acc = {0.f, 0.f, 0.f, 0.f};
            #pragma unroll
            for (int ks = 0; ks < 2; ++ks) {
                s8v gz = *(const s8v*)(gZ2_u + lr * 72 + 8 * lg + 32 * ks);
                s8v wb = *(const s8v*)(W2bfb + nn * 128 +
                                       ((16 * lg + 64 * ks) ^ ((nn & 7) << 4)));
                acc = MFMA(gz, wb, acc);
            }
            u4v pk;
            #pragma unroll
            for (int r = 0; r < 4; ++r)
                pk[r] = f2bf(acc[r] * dgelu_f(z1f[4*a+r]));
            *(u4v*)(gZ1T_u + nn * 24 + 4 * lg) = pk;
        }
        __syncthreads();

        // ============ P5: Z1b finish -> X2b ; W1 update ; b1 update ========
        #pragma unroll
        for (int a = 0; a < 2; ++a) {
            const int nn = 32 * w + 16 * a + lr;
            s8v ml = ld4z(M1_u + lr * 24 + 4 * lg);
            s8v gr = ld4z(gZ1T_u + nn * 24 + 4 * lg);
            f4v acc = {z1b[4*a], z1b[4*a+1], z1b[4*a+2], z1b[4*a+3]};
            acc = MFMA(ml, gr, acc);
            #pragma unroll
            for (int r = 0; r < 4; ++r)
                X2b_u[(4 * lg + r) * 264 + nn] = f2bf(gelu_f(acc[r]));
        }
        #pragma unroll
        for (int i = 0; i < 8; ++i) {
            const int idx = 8 * w + i;
            const int mt = idx >> 4, nt = idx & 15;
            s8v la = ld4z(XBT64_u + (16 * mt + lr) * 24 + 4 * lg);
            s8v rb = ld4z(gZ1T_u + (16 * nt + lr) * 24 + 4 * lg);
            f4v uz = {0.f, 0.f, 0.f, 0.f};
            uz = MFMA(la, rb, uz);
            u4v pw;
            #pragma unroll
            for (int r = 0; r < 4; ++r) {
                w1r[4*i+r] -= c15 * uz[r];
                pw[r] = f2bf(w1r[4*i+r]);
            }
            const int nn1 = 16 * nt + lr;
            const int d0  = 16 * mt + 4 * lg;
            *(u4v*)(W1Tb + nn1 * 128 + ((2 * d0) ^ ((nn1 & 7) << 4))) = pw;
        }
        if (t < 256) {
            float s = 0.f;
            #pragma unroll
            for (int q = 0; q < 4; ++q) {
                u4v v = *(const u4v*)(gZ1T_u + t * 24 + 4 * q);
                s += bf2f(v[0]) + bf2f(v[1]) + bf2f(v[2]) + bf2f(v[3]);
            }
            b1s[t] -= c15 * s;
        }
        __syncthreads();

        // ===== P6: Attn2/M2 (w0), Z2b-main (w1..4), W2-upd mfma (all) ======
        if (w == 0) {
            f4v at2 = {0.f, 0.f, 0.f, 0.f};
            #pragma unroll
            for (int ks = 0; ks < 8; ++ks) {
                s8v xb2 = *(const s8v*)(X2b_u + lr * 264 + 8 * lg + 32 * ks);
                s8v x2r = *(const s8v*)(X2_u  + lr * 264 + 8 * lg + 32 * ks);
                at2 = MFMA(xb2, x2r, at2);
            }
            #pragma unroll
            for (int r = 0; r < 4; ++r) {
                const int aa = 4 * lg + r;
                float val = (lr <= aa) ? -(cf[aa] * (at2[r] + 1.0f)) : 0.0f;
                M2_u[aa * 24 + lr] = f2bf(val);
            }
        } else if (w <= 4) {
            const int dt = w - 1;
            const float bv = b2s[16 * dt + lr];
            z2bacc = (f4v){bv, bv, bv, bv};
            #pragma unroll
            for (int ks = 0; ks < 8; ++ks) {
                s8v xb2 = *(const s8v*)(X2b_u + lr * 264 + 8 * lg + 32 * ks);
                s8v wt  = *(const s8v*)(W2T_u + (16 * dt + lr) * 264 + 8 * lg + 32 * ks);
                z2bacc = MFMA(xb2, wt, z2bacc);
            }
        }
        #pragma unroll
        for (int i = 0; i < 8; ++i) {
            const int idx = 8 * w + i;
            const int mt = idx >> 2, nt = idx & 3;
            s8v la = ld4z(X2T_u  + (16 * mt + lr) * 24 + 4 * lg);
            s8v rb = ld4z(gZ2T_u + (16 * nt + lr) * 24 + 4 * lg);
            f4v uz = {0.f, 0.f, 0.f, 0.f};
            uz = MFMA(la, rb, uz);
            #pragma unroll
            for (int r = 0; r < 4; ++r) w2r[4*i+r] -= c15 * uz[r];
        }
        __syncthreads();

        // ===== P7: Z2b finalize + store bf16 ; W2 shadow writes ; b2 upd ===
        if (w >= 1 && w <= 4) {
            const int dt = w - 1;
            s8v ml = ld4z(M2_u + lr * 24 + 4 * lg);
            s8v gr = ld4z(gZ2T_u + (16 * dt + lr) * 24 + 4 * lg);
            z2bacc = MFMA(ml, gr, z2bacc);
            #pragma unroll
            for (int r = 0; r < 4; ++r)
                XCWb[((long)(bb * L_ + l0 + 4 * lg + r)) * C_ + h * HD_ + 16 * dt + lr]
                    = f2bf(z2bacc[r]);
        }
        #pragma unroll
        for (int i = 0; i < 8; ++i) {
            const int idx = 8 * w + i;
            const int mt = idx >> 2, nt = idx & 3;
            const int j0 = 16 * mt + 4 * lg, dn = 16 * nt + lr;
            u4v pw;
            #pragma unroll
            for (int r = 0; r < 4; ++r) pw[r] = f2bf(w2r[4*i+r]);
            *(u4v*)(W2T_u + dn * 264 + j0) = pw;
            #pragma unroll
            for (int r = 0; r < 4; ++r) {
                const int j = j0 + r;
                *(ushort_t*)(W2bfb + j * 128 + ((2 * dn) ^ ((j & 7) << 4))) = pw[r];
            }
        }
        if (t < 64) {
            float s = 0.f;
            #pragma unroll
            for (int q = 0; q < 4; ++q) {
                u4v v = *(const u4v*)(gZ2T_u + t * 24 + 4 * q);
                s += bf2f(v[0]) + bf2f(v[1]) + bf2f(v[2]) + bf2f(v[3]);
            }
            b2s[t] -= c15 * s;
        }
        __syncthreads();
    }
}

// ---------------------------------------------------------------------------
extern "C" void kernel_launch(void* const* d_in, const int* in_sizes, int n_in,
                              void* d_out, int out_size, void* d_ws, size_t ws_size,
                              hipStream_t stream)
{
    const float* hidden = (const float*)d_in[0];
    const float* Wq  = (const float*)d_in[1];
    const float* Wk  = (const float*)d_in[2];
    const float* Wv  = (const float*)d_in[3];
    const float* Wo  = (const float*)d_in[4];
    const float* W1g = (const float*)d_in[5];
    const float* b1g = (const float*)d_in[6];
    const float* W2g = (const float*)d_in[7];
    const float* b2g = (const float*)d_in[8];
    const float* lnw = (const float*)d_in[9];
    const float* lnb = (const float*)d_in[10];
    const float* gw  = (const float*)d_in[11];
    const float* gb  = (const float*)d_in[12];
    float* out = (float*)d_out;
    char* ws  = (char*)d_ws;

    // ws layout (bytes)
    ushort_t* bfbuf  = (ushort_t*)(ws);                  // hidden_bf + 4 W_bf
    ushort_t* hid_bf = bfbuf;
    ushort_t* Wq_bf  = bfbuf + 8388608L;
    ushort_t* Wk_bf  = Wq_bf + 1048576L;
    ushort_t* Wv_bf  = Wk_bf + 1048576L;
    ushort_t* Wo_bf  = Wv_bf + 1048576L;
    float*    XA     = (float*)(ws + 25165824L);         // 33.5 MB
    ushort_t* XB_bf  = (ushort_t*)(ws + 58720256L);      // 16.8 MB
    ushort_t* XC_bf  = (ushort_t*)(ws + 75497472L);      // 16.8 MB
    ushort_t* XCW_bf = (ushort_t*)(ws + 92274688L);      // 16.8 MB
    float*    coeff  = (float*)(ws + 109051904L);        // 0.5 MB

    hipFuncSetAttribute(reinterpret_cast<const void*>(ttt_scan),
                        hipFuncAttributeMaxDynamicSharedMemorySize,
                        SCAN_LDS_BYTES);

    cast_kernel<<<6144, 256, 0, stream>>>(hidden, Wq, Wk, Wv, Wo, bfbuf);
    gemm_bf16<<<512, 256, 0, stream>>>(hid_bf, Wq_bf, XA,    0);
    gemm_bf16<<<512, 256, 0, stream>>>(hid_bf, Wk_bf, XB_bf, 1);
    gemm_bf16<<<512, 256, 0, stream>>>(hid_bf, Wv_bf, XC_bf, 1);
    gate_kernel<<<512, 256, 0, stream>>>(hidden, gw, gb, coeff);
    ttt_scan<<<64, 512, SCAN_LDS_BYTES, stream>>>(XA, XB_bf, XC_bf, coeff,
                                                  W1g, b1g, W2g, b2g,
                                                  lnw, lnb, XCW_bf);
    gemm_bf16<<<512, 256, 0, stream>>>(XCW_bf, Wo_bf, out, 2);
}

// Round 7
// 914.355 us; speedup vs baseline: 9.0400x; 1.2258x over previous
//
#include <hip/hip_runtime.h>
#include <hip/hip_bf16.h>

// ---------------------------------------------------------------------------
// TTT-MLP dual-form. bf16-MFMA GEMMs + MFMA scan (fp32 state/accum).
// B=4, L=2048, C=1024, NH=16, HD=64, INTER=256, K=16, n_chunk=128, LR=1
// ---------------------------------------------------------------------------

#define B_  4
#define L_  2048
#define C_  1024
#define NH_ 16
#define HD_ 64
#define IN_ 256
#define K_  16
#define NCH_ 128
#define EPS_ 1e-6f

typedef unsigned short ushort_t;
typedef __attribute__((ext_vector_type(8))) short  s8v;
typedef __attribute__((ext_vector_type(4))) float  f4v;
typedef __attribute__((ext_vector_type(4))) unsigned short u4v;
typedef __attribute__((ext_vector_type(4))) __bf16 bf4v;

#define MFMA(a,b,c) __builtin_amdgcn_mfma_f32_16x16x32_bf16(a,b,c,0,0,0)

#define LOAD_LDS16(gp, lp) \
  __builtin_amdgcn_global_load_lds((const __attribute__((address_space(1))) void*)(gp), \
                                   (__attribute__((address_space(3))) void*)(lp), 16, 0, 0)

__device__ __forceinline__ ushort_t f2bf(float f) {
    __bf16 h = (__bf16)f;
    return __builtin_bit_cast(ushort_t, h);
}
__device__ __forceinline__ u4v pk4(float a, float b, float c, float d) {
    bf4v h = {(__bf16)a, (__bf16)b, (__bf16)c, (__bf16)d};
    return __builtin_bit_cast(u4v, h);
}
__device__ __forceinline__ float bf2f(ushort_t v) {
    return __uint_as_float(((unsigned int)v) << 16);
}
// gelu(x) = x*(1-r), r = 1/(exp(2u)+1), u = 0.79788456(x+0.044715x^3)
__device__ __forceinline__ float fast_gelu(float x) {
    float u = 0.79788456f * (x + 0.044715f * x * x * x);
    float e = __expf(2.0f * u);
    float r = __builtin_amdgcn_rcpf(e + 1.0f);
    return x - x * r;
}
// dgelu = 2x*e*r^2*(c1+c2 x^2) + 1 - r
__device__ __forceinline__ float fast_dgelu(float x) {
    float x2 = x * x;
    float u = 0.79788456f * x * (1.0f + 0.044715f * x2);
    float e = fminf(__expf(2.0f * u), 1e30f);
    float r = __builtin_amdgcn_rcpf(e + 1.0f);
    return 2.0f * x * e * r * r * (0.79788456f + 0.1070322243f * x2) + 1.0f - r;
}
// K=16 fragment: 4 real bf16 in low half, zero high half (pairing-safe).
__device__ __forceinline__ s8v ld4z(const ushort_t* p) {
    u4v v = *(const u4v*)p;
    s8v a = {(short)v[0], (short)v[1], (short)v[2], (short)v[3], 0, 0, 0, 0};
    return a;
}
__device__ __forceinline__ s8v reg4z(u4v v) {
    s8v a = {(short)v[0], (short)v[1], (short)v[2], (short)v[3], 0, 0, 0, 0};
    return a;
}
// sum over the 16-lane DPP row (all lanes get the total); ctrl is template const
template <int CTRL>
__device__ __forceinline__ float dpp_add(float x) {
    int t = __builtin_amdgcn_update_dpp(0, __builtin_bit_cast(int, x),
                                        CTRL, 0xf, 0xf, true);
    return x + __builtin_bit_cast(float, t);
}
__device__ __forceinline__ float row16_sum(float x) {
    x = dpp_add<0xB1>(x);    // quad_perm(1,0,3,2)
    x = dpp_add<0x4E>(x);    // quad_perm(2,3,0,1)
    x = dpp_add<0x124>(x);   // row_ror:4
    x = dpp_add<0x128>(x);   // row_ror:8
    return x;
}

// ---------------------------------------------------------------------------
// Cast fp32 -> bf16: hidden then Wq,Wk,Wv,Wo contiguous.
// ---------------------------------------------------------------------------
__global__ void __launch_bounds__(256)
cast_kernel(const float* __restrict__ hid, const float* __restrict__ wq,
            const float* __restrict__ wk, const float* __restrict__ wv,
            const float* __restrict__ wo, ushort_t* __restrict__ dst)
{
    const long i = ((long)blockIdx.x * 256 + threadIdx.x) * 8;
    const float* src; long off;
    if (i < 8388608L)        { src = hid; off = i; }
    else if (i < 9437184L)   { src = wq;  off = i - 8388608L; }
    else if (i < 10485760L)  { src = wk;  off = i - 9437184L; }
    else if (i < 11534336L)  { src = wv;  off = i - 10485760L; }
    else                     { src = wo;  off = i - 11534336L; }
    float4 a = *(const float4*)(src + off);
    float4 b = *(const float4*)(src + off + 4);
    *(u4v*)(dst + i)     = pk4(a.x, a.y, a.z, a.w);
    *(u4v*)(dst + i + 4) = pk4(b.x, b.y, b.z, b.w);
}

// ---------------------------------------------------------------------------
// bf16 MFMA GEMM (unchanged structure from round 3)
// ---------------------------------------------------------------------------
__global__ void __launch_bounds__(256, 2)
gemm_bf16(const ushort_t* __restrict__ A, const ushort_t* __restrict__ Bm,
          void* __restrict__ outp, int mode)
{
    __shared__ char lds[16384];
    char* Al = lds;
    char* Bl = lds + 8192;
    const int t  = threadIdx.x;
    const int w  = t >> 6, l = t & 63;
    const int lr = l & 15, lg = l >> 4;
    const int wm = w >> 1, wn = w & 1;
    const int wg = blockIdx.x;
    const int m0 = (wg >> 3) * 128, n0 = (wg & 7) * 128;

    f4v acc[4][4];
    #pragma unroll
    for (int i = 0; i < 4; ++i)
        #pragma unroll
        for (int j = 0; j < 4; ++j)
            acc[i][j] = (f4v){0.f, 0.f, 0.f, 0.f};

    const long arow0 = (long)(m0 + w * 16 + lr) * C_ + lg * 8;
    const long arow1 = (long)(m0 + (w + 4) * 16 + lr) * C_ + lg * 8;
    const long brow0 = (long)(n0 + w * 16 + lr) * C_ + lg * 8;
    const long brow1 = (long)(n0 + (w + 4) * 16 + lr) * C_ + lg * 8;

    for (int ks = 0; ks < C_ / 32; ++ks) {
        const int k0 = ks * 32;
        LOAD_LDS16(A  + arow0 + k0, Al + w * 1024);
        LOAD_LDS16(A  + arow1 + k0, Al + (w + 4) * 1024);
        LOAD_LDS16(Bm + brow0 + k0, Bl + w * 1024);
        LOAD_LDS16(Bm + brow1 + k0, Bl + (w + 4) * 1024);
        __syncthreads();
        s8v af[4], bfr[4];
        #pragma unroll
        for (int i = 0; i < 4; ++i)
            af[i] = *(const s8v*)(Al + (wm * 4 + i) * 1024 + l * 16);
        #pragma unroll
        for (int j = 0; j < 4; ++j)
            bfr[j] = *(const s8v*)(Bl + (wn * 4 + j) * 1024 + l * 16);
        #pragma unroll
        for (int i = 0; i < 4; ++i)
            #pragma unroll
            for (int j = 0; j < 4; ++j)
                acc[i][j] = MFMA(af[i], bfr[j], acc[i][j]);
        __syncthreads();
    }

    #pragma unroll
    for (int i = 0; i < 4; ++i) {
        #pragma unroll
        for (int j = 0; j < 4; ++j) {
            #pragma unroll
            for (int r = 0; r < 4; ++r) {
                const int grow = m0 + wm * 64 + i * 16 + lg * 4 + r;
                const int gcol = n0 + wn * 64 + j * 16 + lr;
                const float v = acc[i][j][r];
                if (mode == 2) {
                    ((float*)outp)[(long)grow * C_ + gcol] = v;
                } else {
                    const int bbv = grow >> 11, ll = grow & 2047;
                    const int hv = gcol >> 6, dv = gcol & 63;
                    const long addr = ((long)(bbv * NH_ + hv) * L_ + ll) * HD_ + dv;
                    if (mode == 0) ((float*)outp)[addr] = v;
                    else           ((ushort_t*)outp)[addr] = f2bf(v);
                }
            }
        }
    }
}

// ---------------------------------------------------------------------------
// Gate (unchanged)
// ---------------------------------------------------------------------------
__global__ void __launch_bounds__(256)
gate_kernel(const float* __restrict__ X, const float* __restrict__ gw,
            const float* __restrict__ gb, float* __restrict__ coeff)
{
    __shared__ float Xs[16][132];
    __shared__ float Gs[16][132];
    const int t = threadIdx.x;
    const int row0 = blockIdx.x * 16;
    const int lsub = t >> 4, hh = t & 15;
    const int sr = t >> 4, sc0 = (t & 15) * 8;

    float accv = 0.f;
    for (int cb = 0; cb < C_; cb += 128) {
        float4 x0 = *(const float4*)&X [(long)(row0 + sr) * C_ + cb + sc0];
        float4 x1 = *(const float4*)&X [(long)(row0 + sr) * C_ + cb + sc0 + 4];
        float4 g0 = *(const float4*)&gw[(long)sr * C_ + cb + sc0];
        float4 g1 = *(const float4*)&gw[(long)sr * C_ + cb + sc0 + 4];
        *(float4*)&Xs[sr][sc0]     = x0; *(float4*)&Xs[sr][sc0 + 4] = x1;
        *(float4*)&Gs[sr][sc0]     = g0; *(float4*)&Gs[sr][sc0 + 4] = g1;
        __syncthreads();
        #pragma unroll 8
        for (int c = 0; c < 128; ++c) accv += Xs[lsub][c] * Gs[hh][c];
        __syncthreads();
    }
    const float ilr = 1.0f / (1.0f + __expf(-(accv + gb[hh])));
    const int l  = row0 + lsub;
    const int bb = l >> 11, lb = l & 2047;
    const int n  = lb >> 4, k = lb & 15;
    coeff[((long)(bb * NH_ + hh) * NCH_ + n) * K_ + k] =
        ilr / (64.0f * (float)(k + 1));
}

// ---------------------------------------------------------------------------
// MFMA scan. 64 WGs x 512 threads. 7 barriers/chunk, DPP LN, fast gelu.
// T-arrays stride 28; Z2f overlays X2b; M1/M2 share one buffer.
// ---------------------------------------------------------------------------
#define OFF_XBT    0          // [16][72] bf16
#define OFF_XCT    2304       // [16][72]
#define OFF_XBT64  4608       // [64][28]
#define OFF_W1T    8192       // [256][64] swz (128B rows)
#define OFF_W2T    40960      // [64][264]
#define OFF_W2BF   74752      // [256][64] swz (128B rows)
#define OFF_X2     107520     // [16][264]
#define OFF_X2T    115968     // [256][28]
#define OFF_X2B    130304     // [16][264]  (Z2f fp32 [16][68] overlaid)
#define OFF_GZ2    138752     // [16][72]
#define OFF_GZ2T   141056     // [64][28]
#define OFF_GZ1T   144640     // [256][28]
#define OFF_M      158976     // [16][28]  (M1 and M2, disjoint lifetimes)
#define OFF_B1S    159872     // 256 f32
#define OFF_B2S    160896     // 64 f32
#define OFF_LNW    161152
#define OFF_LNB    161408
#define OFF_CF     161664
#define SCAN_LDS_BYTES 161728

__global__ void __launch_bounds__(512, 1)
ttt_scan(const float* __restrict__ XAg, const ushort_t* __restrict__ XBg,
         const ushort_t* __restrict__ XCg, const float* __restrict__ coeff,
         const float* __restrict__ W1g, const float* __restrict__ b1g,
         const float* __restrict__ W2g, const float* __restrict__ b2g,
         const float* __restrict__ lnwg, const float* __restrict__ lnbg,
         ushort_t* __restrict__ XCWb)
{
    extern __shared__ char smb[];
    ushort_t* XBt_u   = (ushort_t*)(smb + OFF_XBT);
    ushort_t* XCt_u   = (ushort_t*)(smb + OFF_XCT);
    ushort_t* XBT64_u = (ushort_t*)(smb + OFF_XBT64);
    char*     W1Tb    = smb + OFF_W1T;
    ushort_t* W2T_u   = (ushort_t*)(smb + OFF_W2T);
    char*     W2bfb   = smb + OFF_W2BF;
    ushort_t* X2_u    = (ushort_t*)(smb + OFF_X2);
    ushort_t* X2T_u   = (ushort_t*)(smb + OFF_X2T);
    ushort_t* X2b_u   = (ushort_t*)(smb + OFF_X2B);
    ushort_t* gZ2_u   = (ushort_t*)(smb + OFF_GZ2);
    ushort_t* gZ2T_u  = (ushort_t*)(smb + OFF_GZ2T);
    ushort_t* gZ1T_u  = (ushort_t*)(smb + OFF_GZ1T);
    ushort_t* M_u     = (ushort_t*)(smb + OFF_M);
    float* Z2f  = (float*)(smb + OFF_X2B);     // overlay (disjoint lifetime)
    float* b1s  = (float*)(smb + OFF_B1S);
    float* b2s  = (float*)(smb + OFF_B2S);
    float* lnws = (float*)(smb + OFF_LNW);
    float* lnbs = (float*)(smb + OFF_LNB);
    float* cf   = (float*)(smb + OFF_CF);

    const int t  = threadIdx.x;
    const int w  = t >> 6;
    const int l  = t & 63;
    const int lr = l & 15;
    const int lg = l >> 4;
    const int bh = blockIdx.x;
    const int h  = bh & 15;
    const int bb = bh >> 4;
    const long base = (long)bh * L_ * HD_;

    // ---- init fp32 state in registers + bf16 LDS shadows
    float w1r[32], w2r[32];
    #pragma unroll
    for (int i = 0; i < 8; ++i) {
        const int idx = 8 * w + i;
        const int mt = idx >> 4, nt = idx & 15;
        const int d0 = 16 * mt + 4 * lg, nn = 16 * nt + lr;
        #pragma unroll
        for (int r = 0; r < 4; ++r)
            w1r[4*i+r] = W1g[(h * HD_ + d0 + r) * IN_ + nn];
        *(u4v*)(W1Tb + nn * 128 + ((2 * d0) ^ ((nn & 7) << 4))) =
            pk4(w1r[4*i], w1r[4*i+1], w1r[4*i+2], w1r[4*i+3]);
    }
    #pragma unroll
    for (int i = 0; i < 8; ++i) {
        const int idx = 8 * w + i;
        const int mt = idx >> 2, nt = idx & 3;
        const int j0 = 16 * mt + 4 * lg, dn = 16 * nt + lr;
        #pragma unroll
        for (int r = 0; r < 4; ++r)
            w2r[4*i+r] = W2g[(h * IN_ + j0 + r) * HD_ + dn];
        u4v pw = pk4(w2r[4*i], w2r[4*i+1], w2r[4*i+2], w2r[4*i+3]);
        *(u4v*)(W2T_u + dn * 264 + j0) = pw;
        #pragma unroll
        for (int r = 0; r < 4; ++r) {
            const int j = j0 + r;
            *(ushort_t*)(W2bfb + j * 128 + ((2 * dn) ^ ((j & 7) << 4))) = pw[r];
        }
    }
    if (t < 256) b1s[t] = b1g[h * IN_ + t];
    if (t < 64) {
        b2s[t]  = b2g[h * HD_ + t];
        lnws[t] = lnwg[h * HD_ + t];
        lnbs[t] = lnbg[h * HD_ + t];
    }
    __syncthreads();

    float z1f[8], z1b[8];
    f4v z2bacc;

    // ---- prefetch chunk 0 inputs
    const int pkk = t >> 4, pd0 = (t & 15) * 4;
    u4v pf_b, pf_c; float4 pf_a; float pf_cf;
    if (t < 256) {
        pf_b = *(const u4v*)(XBg + base + (long)pkk * HD_ + pd0);
        pf_c = *(const u4v*)(XCg + base + (long)pkk * HD_ + pd0);
        pf_a = *(const float4*)&XAg[base + (long)pkk * HD_ + pd0];
    }
    if (t < 16) pf_cf = coeff[(long)bh * NCH_ * K_ + t];

    for (int n = 0; n < NCH_; ++n) {
        const int l0 = n << 4;
        float4 cur_a = pf_a;

        // ================= P0: write prefetched XB/XC/coeff to LDS ========
        if (t < 256) {
            *(u4v*)(XBt_u + pkk * 72 + pd0) = pf_b;
            XBT64_u[(pd0+0) * 28 + pkk] = pf_b[0];
            XBT64_u[(pd0+1) * 28 + pkk] = pf_b[1];
            XBT64_u[(pd0+2) * 28 + pkk] = pf_b[2];
            XBT64_u[(pd0+3) * 28 + pkk] = pf_b[3];
            *(u4v*)(XCt_u + pkk * 72 + pd0) = pf_c;
        }
        if (t < 16) cf[t] = pf_cf;
        __syncthreads();                                  // B0
        const float c15 = cf[15];

        // ---- issue prefetch for chunk n+1
        if (n + 1 < NCH_) {
            const long nb = base + (long)(l0 + 16 + pkk) * HD_ + pd0;
            if (t < 256) {
                pf_b = *(const u4v*)(XBg + nb);
                pf_c = *(const u4v*)(XCg + nb);
                pf_a = *(const float4*)&XAg[nb];
            }
            if (t < 16) pf_cf = coeff[((long)bh * NCH_ + n + 1) * K_ + t];
        }

        // ================= P1: Z1 + Z1b-init, gelu, X2/X2T =================
        #pragma unroll
        for (int a = 0; a < 2; ++a) {
            const int nn = 32 * w + 16 * a + lr;
            const float bv = b1s[nn];
            f4v accZ = {bv, bv, bv, bv};
            f4v accB = accZ;
            #pragma unroll
            for (int ks = 0; ks < 2; ++ks) {
                s8v xb = *(const s8v*)(XBt_u + lr * 72 + 8 * lg + 32 * ks);
                s8v xc = *(const s8v*)(XCt_u + lr * 72 + 8 * lg + 32 * ks);
                s8v wf = *(const s8v*)(W1Tb + nn * 128 +
                                       ((16 * lg + 64 * ks) ^ ((nn & 7) << 4)));
                accZ = MFMA(xb, wf, accZ);
                accB = MFMA(xc, wf, accB);
            }
            float gl[4];
            #pragma unroll
            for (int r = 0; r < 4; ++r) {
                z1f[4*a+r] = accZ[r];
                z1b[4*a+r] = accB[r];
                gl[r] = fast_gelu(accZ[r]);
            }
            u4v pkT = pk4(gl[0], gl[1], gl[2], gl[3]);
            #pragma unroll
            for (int r = 0; r < 4; ++r)
                X2_u[(4 * lg + r) * 264 + nn] = pkT[r];
            *(u4v*)(X2T_u + nn * 28 + 4 * lg) = pkT;
        }
        __syncthreads();                                  // B1

        // ========= P2: Z2 = X2@W2 (w0-3); Attn1 -> M1 (w4) =========
        if (w < 4) {
            f4v acc = {0.f, 0.f, 0.f, 0.f};
            #pragma unroll
            for (int ks = 0; ks < 8; ++ks) {
                s8v xa = *(const s8v*)(X2_u + lr * 264 + 8 * lg + 32 * ks);
                s8v wt = *(const s8v*)(W2T_u + (16 * w + lr) * 264 + 8 * lg + 32 * ks);
                acc = MFMA(xa, wt, acc);
            }
            #pragma unroll
            for (int r = 0; r < 4; ++r)
                Z2f[(4 * lg + r) * 68 + 16 * w + lr] = acc[r];
        } else if (w == 4) {
            f4v at = {0.f, 0.f, 0.f, 0.f};
            #pragma unroll
            for (int ks = 0; ks < 2; ++ks) {
                s8v xc = *(const s8v*)(XCt_u + lr * 72 + 8 * lg + 32 * ks);
                s8v xb = *(const s8v*)(XBt_u + lr * 72 + 8 * lg + 32 * ks);
                at = MFMA(xc, xb, at);
            }
            #pragma unroll
            for (int r = 0; r < 4; ++r) {
                const int aa = 4 * lg + r;
                float val = (lr <= aa) ? -(cf[aa] * (at[r] + 1.0f)) : 0.0f;
                M_u[aa * 28 + lr] = f2bf(val);
            }
        }
        __syncthreads();                                  // B2

        // ================= P3: LN + VJP -> gZ2 (t<256, DPP) ================
        if (t < 256) {
            const int kk = t >> 4, d0 = pd0;
            float4 z = *(float4*)&Z2f[kk * 68 + d0];
            z.x += b2s[d0]; z.y += b2s[d0+1]; z.z += b2s[d0+2]; z.w += b2s[d0+3];
            const float mu = row16_sum(z.x + z.y + z.z + z.w) * (1.0f / 64.0f);
            const float e0 = z.x - mu, e1 = z.y - mu, e2 = z.z - mu, e3 = z.w - mu;
            const float v = row16_sum(e0*e0 + e1*e1 + e2*e2 + e3*e3);
            const float rstd = rsqrtf(v * (1.0f / 64.0f) + EPS_);
            const float xh0 = e0*rstd, xh1 = e1*rstd, xh2 = e2*rstd, xh3 = e3*rstd;
            const float lw0 = lnws[d0+0], lw1 = lnws[d0+1], lw2 = lnws[d0+2], lw3 = lnws[d0+3];
            const float g0 = (lw0*xh0 + lnbs[d0+0]) - cur_a.x;
            const float g1 = (lw1*xh1 + lnbs[d0+1]) - cur_a.y;
            const float g2 = (lw2*xh2 + lnbs[d0+2]) - cur_a.z;
            const float g3 = (lw3*xh3 + lnbs[d0+3]) - cur_a.w;
            const float wg0 = lw0*g0, wg1 = lw1*g1, wg2 = lw2*g2, wg3 = lw3*g3;
            const float mwg  = row16_sum(wg0 + wg1 + wg2 + wg3) * (1.0f / 64.0f);
            const float mwgx = row16_sum(wg0*xh0 + wg1*xh1 + wg2*xh2 + wg3*xh3)
                               * (1.0f / 64.0f);
            u4v pg = pk4(rstd * (wg0 - mwg - xh0 * mwgx),
                         rstd * (wg1 - mwg - xh1 * mwgx),
                         rstd * (wg2 - mwg - xh2 * mwgx),
                         rstd * (wg3 - mwg - xh3 * mwgx));
            *(u4v*)(gZ2_u + kk * 72 + d0) = pg;
            gZ2T_u[(d0+0) * 28 + kk] = pg[0];
            gZ2T_u[(d0+1) * 28 + kk] = pg[1];
            gZ2T_u[(d0+2) * 28 + kk] = pg[2];
            gZ2T_u[(d0+3) * 28 + kk] = pg[3];
        }
        __syncthreads();                                  // B3

        // ==== P4: gZ1 (all) -> gZ1T; X2b = gelu(Z1b + M1@gZ1) (wave-local) ==
        #pragma unroll
        for (int a = 0; a < 2; ++a) {
            const int nn = 32 * w + 16 * a + lr;
            f4v acc = {0.f, 0.f, 0.f, 0.f};
            #pragma unroll
            for (int ks = 0; ks < 2; ++ks) {
                s8v gz = *(const s8v*)(gZ2_u + lr * 72 + 8 * lg + 32 * ks);
                s8v wb = *(const s8v*)(W2bfb + nn * 128 +
                                       ((16 * lg + 64 * ks) ^ ((nn & 7) << 4)));
                acc = MFMA(gz, wb, acc);
            }
            u4v pk = pk4(acc[0] * fast_dgelu(z1f[4*a+0]),
                         acc[1] * fast_dgelu(z1f[4*a+1]),
                         acc[2] * fast_dgelu(z1f[4*a+2]),
                         acc[3] * fast_dgelu(z1f[4*a+3]));
            *(u4v*)(gZ1T_u + nn * 28 + 4 * lg) = pk;
            // X2b: B-fragment rows are this wave's own registers
            s8v ml = ld4z(M_u + lr * 28 + 4 * lg);
            s8v gr = reg4z(pk);
            f4v accB = {z1b[4*a], z1b[4*a+1], z1b[4*a+2], z1b[4*a+3]};
            accB = MFMA(ml, gr, accB);
            #pragma unroll
            for (int r = 0; r < 4; ++r)
                X2b_u[(4 * lg + r) * 264 + nn] = f2bf(fast_gelu(accB[r]));
        }
        __syncthreads();                                  // B4

        // == P5: W1-upd + b1 (all); M2 (w0); Z2b-main (w1-4); W2-upd (all) ==
        #pragma unroll
        for (int i = 0; i < 8; ++i) {
            const int idx = 8 * w + i;
            const int mt = idx >> 4, nt = idx & 15;
            s8v la = ld4z(XBT64_u + (16 * mt + lr) * 28 + 4 * lg);
            s8v rb = ld4z(gZ1T_u + (16 * nt + lr) * 28 + 4 * lg);
            f4v uz = {0.f, 0.f, 0.f, 0.f};
            uz = MFMA(la, rb, uz);
            #pragma unroll
            for (int r = 0; r < 4; ++r) w1r[4*i+r] -= c15 * uz[r];
            const int nn1 = 16 * nt + lr;
            const int d0  = 16 * mt + 4 * lg;
            *(u4v*)(W1Tb + nn1 * 128 + ((2 * d0) ^ ((nn1 & 7) << 4))) =
                pk4(w1r[4*i], w1r[4*i+1], w1r[4*i+2], w1r[4*i+3]);
        }
        if (t < 256) {
            float s = 0.f;
            #pragma unroll
            for (int q = 0; q < 4; ++q) {
                u4v v = *(const u4v*)(gZ1T_u + t * 28 + 4 * q);
                s += bf2f(v[0]) + bf2f(v[1]) + bf2f(v[2]) + bf2f(v[3]);
            }
            b1s[t] -= c15 * s;
        }
        if (w == 0) {
            f4v at2 = {0.f, 0.f, 0.f, 0.f};
            #pragma unroll
            for (int ks = 0; ks < 8; ++ks) {
                s8v xb2 = *(const s8v*)(X2b_u + lr * 264 + 8 * lg + 32 * ks);
                s8v x2r = *(const s8v*)(X2_u  + lr * 264 + 8 * lg + 32 * ks);
                at2 = MFMA(xb2, x2r, at2);
            }
            #pragma unroll
            for (int r = 0; r < 4; ++r) {
                const int aa = 4 * lg + r;
                float val = (lr <= aa) ? -(cf[aa] * (at2[r] + 1.0f)) : 0.0f;
                M_u[aa * 28 + lr] = f2bf(val);
            }
        } else if (w <= 4) {
            const int dt = w - 1;
            const float bv = b2s[16 * dt + lr];
            z2bacc = (f4v){bv, bv, bv, bv};
            #pragma unroll
            for (int ks = 0; ks < 8; ++ks) {
                s8v xb2 = *(const s8v*)(X2b_u + lr * 264 + 8 * lg + 32 * ks);
                s8v wt  = *(const s8v*)(W2T_u + (16 * dt + lr) * 264 + 8 * lg + 32 * ks);
                z2bacc = MFMA(xb2, wt, z2bacc);
            }
        }
        #pragma unroll
        for (int i = 0; i < 8; ++i) {
            const int idx = 8 * w + i;
            const int mt = idx >> 2, nt = idx & 3;
            s8v la = ld4z(X2T_u  + (16 * mt + lr) * 28 + 4 * lg);
            s8v rb = ld4z(gZ2T_u + (16 * nt + lr) * 28 + 4 * lg);
            f4v uz = {0.f, 0.f, 0.f, 0.f};
            uz = MFMA(la, rb, uz);
            #pragma unroll
            for (int r = 0; r < 4; ++r) w2r[4*i+r] -= c15 * uz[r];
        }
        __syncthreads();                                  // B5

        // ===== P6: Z2b finalize + store; W2 shadow writes; b2 update =====
        if (w >= 1 && w <= 4) {
            const int dt = w - 1;
            s8v ml = ld4z(M_u + lr * 28 + 4 * lg);
            s8v gr = ld4z(gZ2T_u + (16 * dt + lr) * 28 + 4 * lg);
            z2bacc = MFMA(ml, gr, z2bacc);
            #pragma unroll
            for (int r = 0; r < 4; ++r)
                XCWb[((long)(bb * L_ + l0 + 4 * lg + r)) * C_ + h * HD_ + 16 * dt + lr]
                    = f2bf(z2bacc[r]);
        }
        #pragma unroll
        for (int i = 0; i < 8; ++i) {
            const int idx = 8 * w + i;
            const int mt = idx >> 2, nt = idx & 3;
            const int j0 = 16 * mt + 4 * lg, dn = 16 * nt + lr;
            u4v pw = pk4(w2r[4*i], w2r[4*i+1], w2r[4*i+2], w2r[4*i+3]);
            *(u4v*)(W2T_u + dn * 264 + j0) = pw;
            #pragma unroll
            for (int r = 0; r < 4; ++r) {
                const int j = j0 + r;
                *(ushort_t*)(W2bfb + j * 128 + ((2 * dn) ^ ((j & 7) << 4))) = pw[r];
            }
        }
        if (t < 64) {
            float s = 0.f;
            #pragma unroll
            for (int q = 0; q < 4; ++q) {
                u4v v = *(const u4v*)(gZ2T_u + t * 28 + 4 * q);
                s += bf2f(v[0]) + bf2f(v[1]) + bf2f(v[2]) + bf2f(v[3]);
            }
            b2s[t] -= c15 * s;
        }
        __syncthreads();                                  // B6
    }
}

// ---------------------------------------------------------------------------
extern "C" void kernel_launch(void* const* d_in, const int* in_sizes, int n_in,
                              void* d_out, int out_size, void* d_ws, size_t ws_size,
                              hipStream_t stream)
{
    const float* hidden = (const float*)d_in[0];
    const float* Wq  = (const float*)d_in[1];
    const float* Wk  = (const float*)d_in[2];
    const float* Wv  = (const float*)d_in[3];
    const float* Wo  = (const float*)d_in[4];
    const float* W1g = (const float*)d_in[5];
    const float* b1g = (const float*)d_in[6];
    const float* W2g = (const float*)d_in[7];
    const float* b2g = (const float*)d_in[8];
    const float* lnw = (const float*)d_in[9];
    const float* lnb = (const float*)d_in[10];
    const float* gw  = (const float*)d_in[11];
    const float* gb  = (const float*)d_in[12];
    float* out = (float*)d_out;
    char* ws  = (char*)d_ws;

    ushort_t* bfbuf  = (ushort_t*)(ws);
    ushort_t* hid_bf = bfbuf;
    ushort_t* Wq_bf  = bfbuf + 8388608L;
    ushort_t* Wk_bf  = Wq_bf + 1048576L;
    ushort_t* Wv_bf  = Wk_bf + 1048576L;
    ushort_t* Wo_bf  = Wv_bf + 1048576L;
    float*    XA     = (float*)(ws + 25165824L);
    ushort_t* XB_bf  = (ushort_t*)(ws + 58720256L);
    ushort_t* XC_bf  = (ushort_t*)(ws + 75497472L);
    ushort_t* XCW_bf = (ushort_t*)(ws + 92274688L);
    float*    coeff  = (float*)(ws + 109051904L);

    (void)hipFuncSetAttribute(reinterpret_cast<const void*>(ttt_scan),
                              hipFuncAttributeMaxDynamicSharedMemorySize,
                              SCAN_LDS_BYTES);

    cast_kernel<<<6144, 256, 0, stream>>>(hidden, Wq, Wk, Wv, Wo, bfbuf);
    gemm_bf16<<<512, 256, 0, stream>>>(hid_bf, Wq_bf, XA,    0);
    gemm_bf16<<<512, 256, 0, stream>>>(hid_bf, Wk_bf, XB_bf, 1);
    gemm_bf16<<<512, 256, 0, stream>>>(hid_bf, Wv_bf, XC_bf, 1);
    gate_kernel<<<512, 256, 0, stream>>>(hidden, gw, gb, coeff);
    ttt_scan<<<64, 512, SCAN_LDS_BYTES, stream>>>(XA, XB_bf, XC_bf, coeff,
                                                  W1g, b1g, W2g, b2g,
                                                  lnw, lnb, XCW_bf);
    gemm_bf16<<<512, 256, 0, stream>>>(XCW_bf, Wo_bf, out, 2);
}